// Round 8
// baseline (1061.713 us; speedup 1.0000x reference)
//
#include <hip/hip_runtime.h>

// ---------------------------------------------------------------------------
// NetGINE round 8: fuse bond-encoder GEMM + gather + scatter-aggregate.
//   prep_kernel: weights -> frag-layout bf16 buffers
//   CSR-order build: hist + hierarchical scan + fused fill/perm (src,dst,attr)
//   init_z: z = (1+eps)*h (zero-padded to RB)
//   fused_edge_kernel: per 16-edge tile (dst-sorted): e=relu(attr@be1)@be2 via
//       MFMA in regs -> m=relu(h[src]+e) -> run-merged atomic adds into z.
//       No ebond materialization (saves ~700 MB HBM traffic/call).
//   node_mfma_kernel: x = bn(relu(relu(z@m1)@m2))
//   pool + FC head
// ---------------------------------------------------------------------------

typedef __attribute__((ext_vector_type(8))) short short8v;
typedef __attribute__((ext_vector_type(4))) float float4v;

__device__ __forceinline__ unsigned short f2bf(float f) {  // RNE f32->bf16
  unsigned u = __float_as_uint(f);
  u += 0x7fff + ((u >> 16) & 1);
  return (unsigned short)(u >> 16);
}
__device__ __forceinline__ float bf2f(unsigned short s) {
  return __uint_as_float(((unsigned)s) << 16);
}
__device__ __forceinline__ float4v mfma16(short8v a, short8v b, float4v c) {
  return __builtin_amdgcn_mfma_f32_16x16x32_bf16(a, b, c, 0, 0, 0);
}

// ---------------- weight prep: frag-layout bf16 buffers ----------------
__global__ __launch_bounds__(256) void prep_kernel(
    const float* c1be2, const float* c2be2, const float* c3be2,
    const float* c1m1, const float* c2m1, const float* c3m1,
    const float* c1m2, const float* c2m2, const float* c3m2,
    const float* c1be1, const float* c2be1, const float* c3be1,
    unsigned short* FB, float* B1P) {
  int job = blockIdx.x;
  if (job < 9) {
    const float* W = nullptr; int ldw = 0, kmax = 0, nmax = 0, NT = 0, KT = 0;
    switch (job) {
      case 0: W = c1be2; ldw = 28; kmax = 28; nmax = 28; NT = 2; KT = 1; break;
      case 1: W = c2be2; ldw = 64; kmax = 64; nmax = 64; NT = 4; KT = 2; break;
      case 2: W = c3be2; ldw = 64; kmax = 64; nmax = 64; NT = 4; KT = 2; break;
      case 3: W = c1m1;  ldw = 28; kmax = 28; nmax = 28; NT = 2; KT = 1; break;
      case 4: W = c2m1;  ldw = 64; kmax = 64; nmax = 64; NT = 4; KT = 2; break;
      case 5: W = c3m1;  ldw = 64; kmax = 64; nmax = 64; NT = 4; KT = 2; break;
      case 6: W = c1m2;  ldw = 64; kmax = 28; nmax = 64; NT = 4; KT = 1; break;
      case 7: W = c2m2;  ldw = 64; kmax = 64; nmax = 64; NT = 4; KT = 2; break;
      case 8: W = c3m2;  ldw = 64; kmax = 64; nmax = 64; NT = 4; KT = 2; break;
    }
    unsigned short* out = FB + (size_t)job * 4096;
    int total = NT * KT * 512;
    for (int i = threadIdx.x; i < total; i += 256) {
      int fi = i >> 9, l = (i >> 3) & 63, j = i & 7;
      int kt = fi % KT, nt = fi / KT;
      int k = kt * 32 + (l >> 4) * 8 + j;
      int n = nt * 16 + (l & 15);
      float w = (k < kmax && n < nmax) ? W[k * ldw + n] : 0.f;
      out[i] = f2bf(w);
    }
  } else {
    int b = job - 9;
    const float* be1 = (b == 0) ? c1be1 : (b == 1) ? c2be1 : c3be1;
    int DE = (b == 0) ? 28 : 64;
    float* out = B1P + (size_t)b * (64 * 48);
    for (int i = threadIdx.x; i < 64 * 48; i += 256) {
      int l = i / 48, r = i % 48;
      int c = r / 16, kk = r % 16;
      int kt = kk >> 3, j = kk & 7;
      int k = kt * 32 + ((l >> 4) & 3) * 8 + j;
      out[i] = (k < DE) ? be1[c * DE + k] : 0.f;
    }
  }
}

// ---------------- CSR build ----------------

__global__ void hist_kernel(const int* __restrict__ idx, int* __restrict__ cnt, int n) {
  int i = blockIdx.x * blockDim.x + threadIdx.x;
  int stride = gridDim.x * blockDim.x;
  for (; i < n; i += stride) atomicAdd(&cnt[idx[i]], 1);
}

__global__ void fill_perm_kernel(const int* __restrict__ srcs, const int* __restrict__ dsts,
                                 const float* __restrict__ eattr, int* __restrict__ cursor,
                                 int* __restrict__ src_s, int* __restrict__ dst_s,
                                 float4* __restrict__ attr_s, int n) {
  int i = blockIdx.x * blockDim.x + threadIdx.x;
  int stride = gridDim.x * blockDim.x;
  for (; i < n; i += stride) {
    int d = dsts[i];
    int p = atomicAdd(&cursor[d], 1);
    src_s[p] = srcs[i];
    dst_s[p] = d;
    attr_s[p] = make_float4(eattr[i * 3 + 0], eattr[i * 3 + 1], eattr[i * 3 + 2], 0.f);
  }
}

__global__ __launch_bounds__(256) void block_reduce_kernel(
    const int* __restrict__ cnt, int* __restrict__ bsum, int n) {
  __shared__ int s[256];
  int i = blockIdx.x * 256 + threadIdx.x;
  s[threadIdx.x] = (i < n) ? cnt[i] : 0;
  __syncthreads();
  for (int d = 128; d > 0; d >>= 1) {
    if (threadIdx.x < d) s[threadIdx.x] += s[threadIdx.x + d];
    __syncthreads();
  }
  if (threadIdx.x == 0) bsum[blockIdx.x] = s[0];
}

__global__ __launch_bounds__(256) void bsum_scan_kernel(int* __restrict__ bsum, int nb) {
  __shared__ int s[1024];
  for (int i = threadIdx.x; i < 1024; i += 256) s[i] = (i < nb) ? bsum[i] : 0;
  __syncthreads();
  if (threadIdx.x == 0) {
    int acc = 0;
    for (int i = 0; i < nb; i++) { int t = s[i]; s[i] = acc; acc += t; }
  }
  __syncthreads();
  for (int i = threadIdx.x; i < nb; i += 256) bsum[i] = s[i];
}

__global__ __launch_bounds__(256) void scan_apply_kernel(
    const int* __restrict__ cnt, const int* __restrict__ bsum,
    int* __restrict__ cursor, int n) {
  __shared__ int s[256];
  int b = blockIdx.x;
  int i = b * 256 + threadIdx.x;
  int v = (i < n) ? cnt[i] : 0;
  s[threadIdx.x] = v;
  __syncthreads();
  for (int d = 1; d < 256; d <<= 1) {
    int t = (threadIdx.x >= d) ? s[threadIdx.x - d] : 0;
    __syncthreads();
    s[threadIdx.x] += t;
    __syncthreads();
  }
  int excl = s[threadIdx.x] - v + bsum[b];
  if (i < n) cursor[i] = excl;
}

__global__ void boundary_kernel(const int* __restrict__ batch, int* __restrict__ goff,
                                int n, int G) {
  int g = blockIdx.x * blockDim.x + threadIdx.x;
  if (g > G) return;
  int lo = 0, hi = n;
  while (lo < hi) {
    int mid = (lo + hi) >> 1;
    if (batch[mid] < g) lo = mid + 1; else hi = mid;
  }
  goff[g] = lo;
}

// ---------------- z init: z = (1+eps)*h, zero-padded to RB ----------------
template <int DH, int RB>
__global__ __launch_bounds__(256) void init_z_kernel(const float* __restrict__ h,
                                                     const float* __restrict__ epsp,
                                                     float* __restrict__ z, int n_nodes) {
  int i = blockIdx.x * blockDim.x + threadIdx.x;
  if (i >= n_nodes * RB) return;
  int v = i / RB, c = i % RB;
  float val = 0.f;
  if (DH == RB || c < DH) val = (1.f + epsp[0]) * h[(size_t)v * DH + c];
  z[i] = val;
}

// ---------------- fused edge kernel ----------------
// Per 16-edge tile of the dst-sorted edge list:
//   A-frag: t=relu(attr@be1) computed per-lane (edge row = lane&15)
//   e = MFMA(t, be2)  -> lane holds e[row=rr+r][col=nt*16+nc]
//   m = relu(h[src_row] + e)   (h row width == DE)
//   run-merged unsafeAtomicAdd into z[dst][col]  (dsts sorted within tile)
template <int DE>
__global__ __launch_bounds__(256) void fused_edge_kernel(
    const float4* __restrict__ attr_s, const float* __restrict__ b1p,
    const unsigned short* __restrict__ be2f, const float* __restrict__ h,
    const int* __restrict__ src_s, const int* __restrict__ dst_s,
    float* __restrict__ z, int E) {
  constexpr int KT = (DE + 31) / 32;
  constexpr int NT = (DE + 15) / 16;
  constexpr int RB = KT * 32;
  int lane = threadIdx.x & 63;
  int nc = lane & 15, kg = lane >> 4, rr = kg * 4;
  int gw = (blockIdx.x * blockDim.x + threadIdx.x) >> 6;
  int nw = (gridDim.x * blockDim.x) >> 6;

  float b1v[3][KT * 8];
#pragma unroll
  for (int c = 0; c < 3; c++)
#pragma unroll
    for (int kk = 0; kk < KT * 8; kk++)
      b1v[c][kk] = b1p[lane * 48 + c * 16 + (kk >> 3) * 8 + (kk & 7)];

  short8v bfrag[NT][KT];
#pragma unroll
  for (int nt = 0; nt < NT; nt++)
#pragma unroll
    for (int kt = 0; kt < KT; kt++)
      bfrag[nt][kt] = *(const short8v*)(be2f + ((nt * KT + kt) * 64 + lane) * 8);

  bool colv[NT];
#pragma unroll
  for (int nt = 0; nt < NT; nt++) colv[nt] = (DE == 64) || (nt * 16 + nc < DE);

  int ntiles = (E + 15) >> 4;
  for (int tile = gw; tile < ntiles; tile += nw) {
    int j0 = tile << 4;
    // --- bond encoder: A-frag for edge row nc ---
    float4 a = attr_s[min(j0 + nc, E - 1)];
    short8v af[KT];
#pragma unroll
    for (int kt = 0; kt < KT; kt++)
#pragma unroll
      for (int j = 0; j < 8; j++) {
        int kk = kt * 8 + j;
        float t = fmaxf(fmaf(a.x, b1v[0][kk], fmaf(a.y, b1v[1][kk], a.z * b1v[2][kk])), 0.f);
        af[kt][j] = (short)f2bf(t);
      }
    float4v acc[NT];
#pragma unroll
    for (int nt = 0; nt < NT; nt++) {
      acc[nt] = (float4v){0.f, 0.f, 0.f, 0.f};
#pragma unroll
      for (int kt = 0; kt < KT; kt++) acc[nt] = mfma16(af[kt], bfrag[nt][kt], acc[nt]);
    }
    // --- rows owned by this lane: j0+rr+r ---
    int s_r[4], d_r[4];
    bool rv[4];
#pragma unroll
    for (int r = 0; r < 4; r++) {
      int jr = j0 + rr + r;
      rv[r] = jr < E;
      jr = min(jr, E - 1);
      s_r[r] = src_s[jr];
      d_r[r] = dst_s[jr];
    }
    // --- m = relu(h[src] + e) ; 16 independent gathers in flight ---
    float m[4][NT];
#pragma unroll
    for (int r = 0; r < 4; r++)
#pragma unroll
      for (int nt = 0; nt < NT; nt++) {
        float hv = (rv[r] && colv[nt]) ? h[(size_t)s_r[r] * DE + nt * 16 + nc] : 0.f;
        m[r][nt] = (rv[r] && colv[nt]) ? fmaxf(hv + acc[nt][r], 0.f) : 0.f;
      }
    // --- run-merged scatter (dsts sorted within the 4-row group) ---
    float racc[NT];
#pragma unroll
    for (int nt = 0; nt < NT; nt++) racc[nt] = m[0][nt];
    int cd = d_r[0];
#pragma unroll
    for (int r = 1; r < 4; r++) {
      if (d_r[r] != cd) {
#pragma unroll
        for (int nt = 0; nt < NT; nt++)
          if (colv[nt]) unsafeAtomicAdd(&z[(size_t)cd * RB + nt * 16 + nc], racc[nt]);
#pragma unroll
        for (int nt = 0; nt < NT; nt++) racc[nt] = m[r][nt];
        cd = d_r[r];
      } else {
#pragma unroll
        for (int nt = 0; nt < NT; nt++) racc[nt] += m[r][nt];
      }
    }
#pragma unroll
    for (int nt = 0; nt < NT; nt++)
      if (colv[nt]) unsafeAtomicAdd(&z[(size_t)cd * RB + nt * 16 + nc], racc[nt]);
  }
}

// ---------------- node MLP + relu + BN (MFMA) ----------------
template <int DIN>
__global__ __launch_bounds__(256) void node_mfma_kernel(
    const float* __restrict__ z, const unsigned short* __restrict__ m1f_g,
    const unsigned short* __restrict__ m2f_g, const float* __restrict__ bng,
    const float* __restrict__ bnb, const float* __restrict__ bnm,
    const float* __restrict__ bnv, float* __restrict__ xout, int n_nodes) {
  constexpr int KT = (DIN + 31) / 32;
  constexpr int NTH = (DIN + 15) / 16;
  constexpr int ZR = KT * 32;
  constexpr int LROW = 64 * 2 + 16;
  __shared__ __attribute__((aligned(16))) char lds_all[4 * 16 * LROW];
  char* yl = lds_all + (threadIdx.x >> 6) * (16 * LROW);
  int lane = threadIdx.x & 63;
  int nc = lane & 15, kg = lane >> 4, rr = kg * 4;
  int gw = (blockIdx.x * blockDim.x + threadIdx.x) >> 6;
  int nw = (gridDim.x * blockDim.x) >> 6;

  short8v m1f[NTH][KT], m2f[4][KT];
#pragma unroll
  for (int nt = 0; nt < NTH; nt++)
#pragma unroll
    for (int kt = 0; kt < KT; kt++)
      m1f[nt][kt] = *(const short8v*)(m1f_g + ((nt * KT + kt) * 64 + lane) * 8);
#pragma unroll
  for (int nt = 0; nt < 4; nt++)
#pragma unroll
    for (int kt = 0; kt < KT; kt++)
      m2f[nt][kt] = *(const short8v*)(m2f_g + ((nt * KT + kt) * 64 + lane) * 8);

  float scv[4], shv[4];
#pragma unroll
  for (int nt = 0; nt < 4; nt++) {
    int f = nt * 16 + nc;
    float sc = bng[f] * rsqrtf(bnv[f] + 1e-5f);
    scv[nt] = sc;
    shv[nt] = bnb[f] - bnm[f] * sc;
  }

  int ntiles = (n_nodes + 15) >> 4;
  for (int tile = gw; tile < ntiles; tile += nw) {
    int v0 = tile << 4;
    int vr = min(v0 + nc, n_nodes - 1);
    short8v af[KT];
#pragma unroll
    for (int kt = 0; kt < KT; kt++) {
      const float* zp = z + (size_t)vr * ZR + kt * 32 + kg * 8;
      float4 z0 = *(const float4*)(zp);
      float4 z1 = *(const float4*)(zp + 4);
      af[kt][0] = (short)f2bf(z0.x); af[kt][1] = (short)f2bf(z0.y);
      af[kt][2] = (short)f2bf(z0.z); af[kt][3] = (short)f2bf(z0.w);
      af[kt][4] = (short)f2bf(z1.x); af[kt][5] = (short)f2bf(z1.y);
      af[kt][6] = (short)f2bf(z1.z); af[kt][7] = (short)f2bf(z1.w);
    }
    float4v acch[NTH];
#pragma unroll
    for (int nt = 0; nt < NTH; nt++) {
      acch[nt] = (float4v){0.f, 0.f, 0.f, 0.f};
#pragma unroll
      for (int kt = 0; kt < KT; kt++) acch[nt] = mfma16(af[kt], m1f[nt][kt], acch[nt]);
    }
#pragma unroll
    for (int nt = 0; nt < NTH; nt++)
#pragma unroll
      for (int r = 0; r < 4; r++)
        *(unsigned short*)(yl + (rr + r) * LROW + (nt * 16 + nc) * 2) =
            f2bf(fmaxf(acch[nt][r], 0.f));
    asm volatile("" ::: "memory");
    short8v af2[KT];
#pragma unroll
    for (int kt = 0; kt < KT; kt++)
      af2[kt] = *(const short8v*)(yl + nc * LROW + kg * 16 + kt * 64);
    float4v acco[4];
#pragma unroll
    for (int nt = 0; nt < 4; nt++) {
      acco[nt] = (float4v){0.f, 0.f, 0.f, 0.f};
#pragma unroll
      for (int kt = 0; kt < KT; kt++) acco[nt] = mfma16(af2[kt], m2f[nt][kt], acco[nt]);
    }
#pragma unroll
    for (int nt = 0; nt < 4; nt++)
#pragma unroll
      for (int r = 0; r < 4; r++) {
        int v = v0 + rr + r;
        if (v < n_nodes)
          xout[(size_t)v * 64 + nt * 16 + nc] =
              fmaf(fmaxf(acco[nt][r], 0.f), scv[nt], shv[nt]);
      }
    asm volatile("" ::: "memory");
  }
}

// ---------------- graph mean-pool of concat(x1..x4) ----------------
__global__ __launch_bounds__(256) void pool_kernel(
    const float* __restrict__ x1, const float* __restrict__ x2,
    const float* __restrict__ x3, const float* __restrict__ x4,
    const int* __restrict__ goff, float* __restrict__ pooled, int G) {
  int g = blockIdx.x;
  int c = threadIdx.x;
  int sel = c >> 6, f = c & 63;
  const float* x = (sel == 0) ? x1 : (sel == 1) ? x2 : (sel == 2) ? x3 : x4;
  int s = goff[g], e = goff[g + 1];
  float acc = 0.f;
  for (int v = s; v < e; v++) acc += x[(size_t)v * 64 + f];
  float cnt = (float)(e - s);
  pooled[g * 256 + c] = acc / fmaxf(cnt, 1.0f);
}

// ---------------- FC head ----------------
__global__ __launch_bounds__(64) void head_kernel(
    const float* __restrict__ pooled,
    const float* __restrict__ w1, const float* __restrict__ b1,
    const float* __restrict__ w2, const float* __restrict__ b2,
    const float* __restrict__ w3, const float* __restrict__ b3,
    const float* __restrict__ w4, const float* __restrict__ b4,
    float* __restrict__ out, int G) {
  int g = blockIdx.x;
  int lane = threadIdx.x;
  __shared__ float sh[256];
  for (int i = lane; i < 256; i += 64) sh[i] = pooled[g * 256 + i];
  __syncthreads();
  float h1 = b1[lane];
#pragma unroll 8
  for (int i = 0; i < 256; i++) h1 = fmaf(sh[i], w1[i * 64 + lane], h1);
  h1 = fmaxf(h1, 0.f);
  __syncthreads();
  sh[lane] = h1;
  __syncthreads();
  float h2 = b2[lane];
#pragma unroll
  for (int i = 0; i < 64; i++) h2 = fmaf(sh[i], w2[i * 64 + lane], h2);
  h2 = fmaxf(h2, 0.f);
  __syncthreads();
  sh[lane] = h2;
  __syncthreads();
  float h3 = b3[lane];
#pragma unroll
  for (int i = 0; i < 64; i++) h3 = fmaf(sh[i], w3[i * 64 + lane], h3);
  h3 = fmaxf(h3, 0.f);
  float p = h3 * w4[lane];
  for (int d = 32; d > 0; d >>= 1) p += __shfl_down(p, d);
  if (lane == 0) out[g] = p + b4[0];
}

// ---------------------------------------------------------------------------

extern "C" void kernel_launch(void* const* d_in, const int* in_sizes, int n_in,
                              void* d_out, int out_size, void* d_ws, size_t ws_size,
                              hipStream_t stream) {
  const float* x      = (const float*)d_in[0];
  const float* eattr  = (const float*)d_in[1];
  const float* c1_be1 = (const float*)d_in[2];
  const float* c1_be2 = (const float*)d_in[3];
  const float* c1_m1  = (const float*)d_in[4];
  const float* c1_m2  = (const float*)d_in[5];
  const float* c1_eps = (const float*)d_in[6];
  const float* c2_be1 = (const float*)d_in[7];
  const float* c2_be2 = (const float*)d_in[8];
  const float* c2_m1  = (const float*)d_in[9];
  const float* c2_m2  = (const float*)d_in[10];
  const float* c2_eps = (const float*)d_in[11];
  const float* c3_be1 = (const float*)d_in[12];
  const float* c3_be2 = (const float*)d_in[13];
  const float* c3_m1  = (const float*)d_in[14];
  const float* c3_m2  = (const float*)d_in[15];
  const float* c3_eps = (const float*)d_in[16];
  const float* bn_g[4] = {(const float*)d_in[17], (const float*)d_in[21],
                          (const float*)d_in[25], (const float*)d_in[29]};
  const float* bn_b[4] = {(const float*)d_in[18], (const float*)d_in[22],
                          (const float*)d_in[26], (const float*)d_in[30]};
  const float* bn_m[4] = {(const float*)d_in[19], (const float*)d_in[23],
                          (const float*)d_in[27], (const float*)d_in[31]};
  const float* bn_v[4] = {(const float*)d_in[20], (const float*)d_in[24],
                          (const float*)d_in[28], (const float*)d_in[32]};
  const float* fc1_w = (const float*)d_in[33];
  const float* fc1_b = (const float*)d_in[34];
  const float* fc2_w = (const float*)d_in[35];
  const float* fc2_b = (const float*)d_in[36];
  const float* fc3_w = (const float*)d_in[37];
  const float* fc3_b = (const float*)d_in[38];
  const float* fc4_w = (const float*)d_in[39];
  const float* fc4_b = (const float*)d_in[40];
  const int* eidx  = (const int*)d_in[41];
  const int* batch = (const int*)d_in[42];

  const int N = in_sizes[0] / 28;
  const int E = in_sizes[1] / 3;
  const int G = out_size;
  const int* src = eidx;
  const int* dst = eidx + E;
  float* outf = (float*)d_out;

  char* p = (char*)d_ws;
  auto alloc = [&](size_t bytes) {
    char* r = p;
    p += (bytes + 255) & ~(size_t)255;
    return r;
  };
  const int NBLK = (N + 255) / 256;
  int* counts   = (int*)alloc((size_t)N * 4);
  int* cursor   = (int*)alloc((size_t)N * 4);
  int* bsum     = (int*)alloc((size_t)NBLK * 4);
  int* goff     = (int*)alloc((size_t)(G + 1) * 4);
  int* src_s    = (int*)alloc((size_t)E * 4);
  int* dst_s    = (int*)alloc((size_t)E * 4);
  float4* attr_s = (float4*)alloc((size_t)E * 16);
  unsigned short* FB = (unsigned short*)alloc(9 * 4096 * 2);
  float* B1P    = (float*)alloc(3 * 64 * 48 * 4);
  float* zbuf   = (float*)alloc((size_t)N * 64 * 4);
  float* x1     = (float*)alloc((size_t)N * 64 * 4);
  float* x2     = (float*)alloc((size_t)N * 64 * 4);
  float* x3     = (float*)alloc((size_t)N * 64 * 4);
  float* x4     = (float*)alloc((size_t)N * 64 * 4);
  float* pooled = (float*)alloc((size_t)G * 256 * 4);
  (void)ws_size; (void)n_in;

  prep_kernel<<<12, 256, 0, stream>>>(c1_be2, c2_be2, c3_be2, c1_m1, c2_m1, c3_m1,
                                      c1_m2, c2_m2, c3_m2, c1_be1, c2_be1, c3_be1,
                                      FB, B1P);
  hipMemsetAsync(counts, 0, (size_t)N * 4, stream);
  hist_kernel<<<1024, 256, 0, stream>>>(dst, counts, E);
  boundary_kernel<<<(G + 128) / 128, 128, 0, stream>>>(batch, goff, N, G);
  block_reduce_kernel<<<NBLK, 256, 0, stream>>>(counts, bsum, N);
  bsum_scan_kernel<<<1, 256, 0, stream>>>(bsum, NBLK);
  scan_apply_kernel<<<NBLK, 256, 0, stream>>>(counts, bsum, cursor, N);
  fill_perm_kernel<<<1024, 256, 0, stream>>>(src, dst, eattr, cursor, src_s, dst_s,
                                             attr_s, E);

  unsigned short* FB_be2[3] = {FB + 0 * 4096, FB + 1 * 4096, FB + 2 * 4096};
  unsigned short* FB_m1[3]  = {FB + 3 * 4096, FB + 4 * 4096, FB + 5 * 4096};
  unsigned short* FB_m2[3]  = {FB + 6 * 4096, FB + 7 * 4096, FB + 8 * 4096};
  float* B1[3] = {B1P, B1P + 64 * 48, B1P + 2 * 64 * 48};

  dim3 blk(256);
  // layer 1
  init_z_kernel<28, 32><<<(N * 32 + 255) / 256, blk, 0, stream>>>(x, c1_eps, zbuf, N);
  fused_edge_kernel<28><<<1024, blk, 0, stream>>>(attr_s, B1[0], FB_be2[0], x,
                                                  src_s, dst_s, zbuf, E);
  node_mfma_kernel<28><<<512, blk, 0, stream>>>(zbuf, FB_m1[0], FB_m2[0], bn_g[0],
                                                bn_b[0], bn_m[0], bn_v[0], x1, N);
  // layer 2
  init_z_kernel<64, 64><<<(N * 64 + 255) / 256, blk, 0, stream>>>(x1, c2_eps, zbuf, N);
  fused_edge_kernel<64><<<1024, blk, 0, stream>>>(attr_s, B1[1], FB_be2[1], x1,
                                                  src_s, dst_s, zbuf, E);
  node_mfma_kernel<64><<<512, blk, 0, stream>>>(zbuf, FB_m1[1], FB_m2[1], bn_g[1],
                                                bn_b[1], bn_m[1], bn_v[1], x2, N);
  // layer 3
  init_z_kernel<64, 64><<<(N * 64 + 255) / 256, blk, 0, stream>>>(x2, c3_eps, zbuf, N);
  fused_edge_kernel<64><<<1024, blk, 0, stream>>>(attr_s, B1[2], FB_be2[2], x2,
                                                  src_s, dst_s, zbuf, E);
  node_mfma_kernel<64><<<512, blk, 0, stream>>>(zbuf, FB_m1[2], FB_m2[2], bn_g[2],
                                                bn_b[2], bn_m[2], bn_v[2], x3, N);
  // layer 4 (conv3 weights reused; e recomputed on the MFMA pipe)
  init_z_kernel<64, 64><<<(N * 64 + 255) / 256, blk, 0, stream>>>(x3, c3_eps, zbuf, N);
  fused_edge_kernel<64><<<1024, blk, 0, stream>>>(attr_s, B1[2], FB_be2[2], x3,
                                                  src_s, dst_s, zbuf, E);
  node_mfma_kernel<64><<<512, blk, 0, stream>>>(zbuf, FB_m1[2], FB_m2[2], bn_g[3],
                                                bn_b[3], bn_m[3], bn_v[3], x4, N);

  pool_kernel<<<G, blk, 0, stream>>>(x1, x2, x3, x4, goff, pooled, G);
  head_kernel<<<G, 64, 0, stream>>>(pooled, fc1_w, fc1_b, fc2_w, fc2_b, fc3_w,
                                    fc3_b, fc4_w, fc4_b, outf, G);
}

// Round 9
// 710.330 us; speedup vs baseline: 1.4947x; 1.4947x over previous
//
#include <hip/hip_runtime.h>

// ---------------------------------------------------------------------------
// NetGINE (round 9 = round 7 base + 4-node-interleaved agg):
//   prep_kernel: weights -> frag-layout bf16 buffers
//   CSR build (by dst): hist + hierarchical scan + fused fill/perm
//   bond_kernel: ebond = relu(attr@be1)@be2, LDS-free MFMA
//   agg_kernel: z[v]=(1+eps)h[v]+sum relu(h[src]+ebond); 4 consecutive nodes
//       per wave, branchless interleaved edge loop (4 independent load chains)
//   node_mfma_kernel: x = bn(relu(relu(z@m1)@m2))
//   pool + FC head
// ---------------------------------------------------------------------------

typedef __attribute__((ext_vector_type(8))) short short8v;
typedef __attribute__((ext_vector_type(4))) float float4v;

__device__ __forceinline__ unsigned short f2bf(float f) {  // RNE f32->bf16
  unsigned u = __float_as_uint(f);
  u += 0x7fff + ((u >> 16) & 1);
  return (unsigned short)(u >> 16);
}
__device__ __forceinline__ float bf2f(unsigned short s) {
  return __uint_as_float(((unsigned)s) << 16);
}
__device__ __forceinline__ float4v mfma16(short8v a, short8v b, float4v c) {
  return __builtin_amdgcn_mfma_f32_16x16x32_bf16(a, b, c, 0, 0, 0);
}

// ---------------- weight prep: frag-layout bf16 buffers ----------------
__global__ __launch_bounds__(256) void prep_kernel(
    const float* c1be2, const float* c2be2, const float* c3be2,
    const float* c1m1, const float* c2m1, const float* c3m1,
    const float* c1m2, const float* c2m2, const float* c3m2,
    const float* c1be1, const float* c2be1, const float* c3be1,
    unsigned short* FB, float* B1P) {
  int job = blockIdx.x;
  if (job < 9) {
    const float* W = nullptr; int ldw = 0, kmax = 0, nmax = 0, NT = 0, KT = 0;
    switch (job) {
      case 0: W = c1be2; ldw = 28; kmax = 28; nmax = 28; NT = 2; KT = 1; break;
      case 1: W = c2be2; ldw = 64; kmax = 64; nmax = 64; NT = 4; KT = 2; break;
      case 2: W = c3be2; ldw = 64; kmax = 64; nmax = 64; NT = 4; KT = 2; break;
      case 3: W = c1m1;  ldw = 28; kmax = 28; nmax = 28; NT = 2; KT = 1; break;
      case 4: W = c2m1;  ldw = 64; kmax = 64; nmax = 64; NT = 4; KT = 2; break;
      case 5: W = c3m1;  ldw = 64; kmax = 64; nmax = 64; NT = 4; KT = 2; break;
      case 6: W = c1m2;  ldw = 64; kmax = 28; nmax = 64; NT = 4; KT = 1; break;
      case 7: W = c2m2;  ldw = 64; kmax = 64; nmax = 64; NT = 4; KT = 2; break;
      case 8: W = c3m2;  ldw = 64; kmax = 64; nmax = 64; NT = 4; KT = 2; break;
    }
    unsigned short* out = FB + (size_t)job * 4096;
    int total = NT * KT * 512;
    for (int i = threadIdx.x; i < total; i += 256) {
      int fi = i >> 9, l = (i >> 3) & 63, j = i & 7;
      int kt = fi % KT, nt = fi / KT;
      int k = kt * 32 + (l >> 4) * 8 + j;
      int n = nt * 16 + (l & 15);
      float w = (k < kmax && n < nmax) ? W[k * ldw + n] : 0.f;
      out[i] = f2bf(w);
    }
  } else {
    int b = job - 9;
    const float* be1 = (b == 0) ? c1be1 : (b == 1) ? c2be1 : c3be1;
    int DE = (b == 0) ? 28 : 64;
    float* out = B1P + (size_t)b * (64 * 48);
    for (int i = threadIdx.x; i < 64 * 48; i += 256) {
      int l = i / 48, r = i % 48;
      int c = r / 16, kk = r % 16;
      int kt = kk >> 3, j = kk & 7;
      int k = kt * 32 + ((l >> 4) & 3) * 8 + j;
      out[i] = (k < DE) ? be1[c * DE + k] : 0.f;
    }
  }
}

// ---------------- CSR build ----------------

__global__ void hist_kernel(const int* __restrict__ idx, int* __restrict__ cnt, int n) {
  int i = blockIdx.x * blockDim.x + threadIdx.x;
  int stride = gridDim.x * blockDim.x;
  for (; i < n; i += stride) atomicAdd(&cnt[idx[i]], 1);
}

__global__ void fill_perm_kernel(const int* __restrict__ srcs, const int* __restrict__ dsts,
                                 const float* __restrict__ eattr, int* __restrict__ cursor,
                                 int* __restrict__ src_s, float4* __restrict__ attr_s,
                                 int n) {
  int i = blockIdx.x * blockDim.x + threadIdx.x;
  int stride = gridDim.x * blockDim.x;
  for (; i < n; i += stride) {
    int d = dsts[i];
    int p = atomicAdd(&cursor[d], 1);
    src_s[p] = srcs[i];
    attr_s[p] = make_float4(eattr[i * 3 + 0], eattr[i * 3 + 1], eattr[i * 3 + 2], 0.f);
  }
}

__global__ __launch_bounds__(256) void block_reduce_kernel(
    const int* __restrict__ cnt, int* __restrict__ bsum, int n) {
  __shared__ int s[256];
  int i = blockIdx.x * 256 + threadIdx.x;
  s[threadIdx.x] = (i < n) ? cnt[i] : 0;
  __syncthreads();
  for (int d = 128; d > 0; d >>= 1) {
    if (threadIdx.x < d) s[threadIdx.x] += s[threadIdx.x + d];
    __syncthreads();
  }
  if (threadIdx.x == 0) bsum[blockIdx.x] = s[0];
}

__global__ __launch_bounds__(256) void bsum_scan_kernel(int* __restrict__ bsum, int nb) {
  __shared__ int s[1024];
  for (int i = threadIdx.x; i < 1024; i += 256) s[i] = (i < nb) ? bsum[i] : 0;
  __syncthreads();
  if (threadIdx.x == 0) {
    int acc = 0;
    for (int i = 0; i < nb; i++) { int t = s[i]; s[i] = acc; acc += t; }
  }
  __syncthreads();
  for (int i = threadIdx.x; i < nb; i += 256) bsum[i] = s[i];
}

__global__ __launch_bounds__(256) void scan_apply_kernel(
    const int* __restrict__ cnt, const int* __restrict__ bsum,
    int* __restrict__ offs, int* __restrict__ cursor, int n) {
  __shared__ int s[256];
  int b = blockIdx.x;
  int i = b * 256 + threadIdx.x;
  int v = (i < n) ? cnt[i] : 0;
  s[threadIdx.x] = v;
  __syncthreads();
  for (int d = 1; d < 256; d <<= 1) {
    int t = (threadIdx.x >= d) ? s[threadIdx.x - d] : 0;
    __syncthreads();
    s[threadIdx.x] += t;
    __syncthreads();
  }
  int excl = s[threadIdx.x] - v + bsum[b];
  if (i < n) { offs[i] = excl; cursor[i] = excl; }
  if (i == n - 1) offs[n] = excl + v;
}

__global__ void boundary_kernel(const int* __restrict__ batch, int* __restrict__ goff,
                                int n, int G) {
  int g = blockIdx.x * blockDim.x + threadIdx.x;
  if (g > G) return;
  int lo = 0, hi = n;
  while (lo < hi) {
    int mid = (lo + hi) >> 1;
    if (batch[mid] < g) lo = mid + 1; else hi = mid;
  }
  goff[g] = lo;
}

// ---------------- bond encoder (MFMA, LDS-free) ----------------
template <int DE>
__global__ __launch_bounds__(256) void bond_kernel(
    const float4* __restrict__ attr_s, const float* __restrict__ b1p,
    const unsigned short* __restrict__ be2f, unsigned short* __restrict__ ebond, int E) {
  constexpr int KT = (DE + 31) / 32;
  constexpr int NT = (DE + 15) / 16;
  constexpr int RB = KT * 32;
  int lane = threadIdx.x & 63;
  int nc = lane & 15, rr = (lane >> 4) * 4;
  int gw = (blockIdx.x * blockDim.x + threadIdx.x) >> 6;
  int nw = (gridDim.x * blockDim.x) >> 6;

  float b1v[3][KT * 8];
#pragma unroll
  for (int c = 0; c < 3; c++)
#pragma unroll
    for (int kk = 0; kk < KT * 8; kk++)
      b1v[c][kk] = b1p[lane * 48 + c * 16 + (kk >> 3) * 8 + (kk & 7)];

  short8v bfrag[NT][KT];
#pragma unroll
  for (int nt = 0; nt < NT; nt++)
#pragma unroll
    for (int kt = 0; kt < KT; kt++)
      bfrag[nt][kt] = *(const short8v*)(be2f + ((nt * KT + kt) * 64 + lane) * 8);

  int ntiles = (E + 15) >> 4;
  for (int tile = gw; tile < ntiles; tile += nw) {
    int j0 = tile << 4;
    float4 a = attr_s[min(j0 + nc, E - 1)];
    short8v af[KT];
#pragma unroll
    for (int kt = 0; kt < KT; kt++)
#pragma unroll
      for (int j = 0; j < 8; j++) {
        int kk = kt * 8 + j;
        float t = fmaxf(fmaf(a.x, b1v[0][kk], fmaf(a.y, b1v[1][kk], a.z * b1v[2][kk])), 0.f);
        af[kt][j] = (short)f2bf(t);
      }
    float4v acc[NT];
#pragma unroll
    for (int nt = 0; nt < NT; nt++) {
      acc[nt] = (float4v){0.f, 0.f, 0.f, 0.f};
#pragma unroll
      for (int kt = 0; kt < KT; kt++) acc[nt] = mfma16(af[kt], bfrag[nt][kt], acc[nt]);
    }
#pragma unroll
    for (int nt = 0; nt < NT; nt++)
#pragma unroll
      for (int r = 0; r < 4; r++) {
        int row = j0 + rr + r;
        if (row < E) ebond[(size_t)row * RB + nt * 16 + nc] = f2bf(acc[nt][r]);
      }
  }
}

// ---------------- edge aggregation (4-node interleave, branchless) ----------------
// Each wave owns 4 consecutive nodes. The edge loop runs to the max degree of
// the 4; all loads issue unconditionally (clamped index) -> 4 independent
// dependency chains in flight; accumulate is predicated.
template <int DH, int RB>
__global__ __launch_bounds__(256) void agg_kernel(
    const float* __restrict__ h, const unsigned short* __restrict__ eb,
    const float* __restrict__ epsp, const int* __restrict__ src_sorted,
    const int* __restrict__ offs, float* __restrict__ zout, int n_nodes, int E) {
  int wid = (blockIdx.x * blockDim.x + threadIdx.x) >> 6;
  int nw = (gridDim.x * blockDim.x) >> 6;
  int lane = threadIdx.x & 63;
  float eps1 = 1.f + epsp[0];
  const bool hl = (DH == 64) || (lane < DH);
  const bool el = (RB == 64) || (lane < RB);

  for (int vb = wid * 4; vb < n_nodes; vb += nw * 4) {
    int o[5];
#pragma unroll
    for (int q = 0; q <= 4; q++) o[q] = offs[min(vb + q, n_nodes)];
    float acc[4];
    int j[4], je[4];
#pragma unroll
    for (int q = 0; q < 4; q++) {
      j[q] = o[q];
      je[q] = o[q + 1];
      bool valid = (vb + q) < n_nodes;
      acc[q] = (valid && hl) ? eps1 * h[(size_t)(vb + q) * DH + lane] : 0.f;
    }
    int steps = max(max(je[0] - j[0], je[1] - j[1]), max(je[2] - j[2], je[3] - j[3]));
    for (int t = 0; t < steps; t++) {
#pragma unroll
      for (int q = 0; q < 4; q++) {
        int jj = j[q] + t;
        bool act = jj < je[q];
        int jc = min(jj, E - 1);
        int s = src_sorted[jc];
        float b = el ? bf2f(eb[(size_t)jc * RB + lane]) : 0.f;
        float hv = hl ? h[(size_t)s * DH + lane] : 0.f;
        float mv = fmaxf(hv + b, 0.f);
        acc[q] += act ? mv : 0.f;
      }
    }
    if (el) {
#pragma unroll
      for (int q = 0; q < 4; q++)
        if ((vb + q) < n_nodes) zout[(size_t)(vb + q) * RB + lane] = acc[q];
    }
  }
}

// ---------------- node MLP + relu + BN (MFMA) ----------------
template <int DIN>
__global__ __launch_bounds__(256) void node_mfma_kernel(
    const float* __restrict__ z, const unsigned short* __restrict__ m1f_g,
    const unsigned short* __restrict__ m2f_g, const float* __restrict__ bng,
    const float* __restrict__ bnb, const float* __restrict__ bnm,
    const float* __restrict__ bnv, float* __restrict__ xout, int n_nodes) {
  constexpr int KT = (DIN + 31) / 32;
  constexpr int NTH = (DIN + 15) / 16;
  constexpr int ZR = KT * 32;
  constexpr int LROW = 64 * 2 + 16;
  __shared__ __attribute__((aligned(16))) char lds_all[4 * 16 * LROW];
  char* yl = lds_all + (threadIdx.x >> 6) * (16 * LROW);
  int lane = threadIdx.x & 63;
  int nc = lane & 15, kg = lane >> 4, rr = kg * 4;
  int gw = (blockIdx.x * blockDim.x + threadIdx.x) >> 6;
  int nw = (gridDim.x * blockDim.x) >> 6;

  short8v m1f[NTH][KT], m2f[4][KT];
#pragma unroll
  for (int nt = 0; nt < NTH; nt++)
#pragma unroll
    for (int kt = 0; kt < KT; kt++)
      m1f[nt][kt] = *(const short8v*)(m1f_g + ((nt * KT + kt) * 64 + lane) * 8);
#pragma unroll
  for (int nt = 0; nt < 4; nt++)
#pragma unroll
    for (int kt = 0; kt < KT; kt++)
      m2f[nt][kt] = *(const short8v*)(m2f_g + ((nt * KT + kt) * 64 + lane) * 8);

  float scv[4], shv[4];
#pragma unroll
  for (int nt = 0; nt < 4; nt++) {
    int f = nt * 16 + nc;
    float sc = bng[f] * rsqrtf(bnv[f] + 1e-5f);
    scv[nt] = sc;
    shv[nt] = bnb[f] - bnm[f] * sc;
  }

  int ntiles = (n_nodes + 15) >> 4;
  for (int tile = gw; tile < ntiles; tile += nw) {
    int v0 = tile << 4;
    int vr = min(v0 + nc, n_nodes - 1);
    short8v af[KT];
#pragma unroll
    for (int kt = 0; kt < KT; kt++) {
      const float* zp = z + (size_t)vr * ZR + kt * 32 + kg * 8;
      float4 z0 = *(const float4*)(zp);
      float4 z1 = *(const float4*)(zp + 4);
      af[kt][0] = (short)f2bf(z0.x); af[kt][1] = (short)f2bf(z0.y);
      af[kt][2] = (short)f2bf(z0.z); af[kt][3] = (short)f2bf(z0.w);
      af[kt][4] = (short)f2bf(z1.x); af[kt][5] = (short)f2bf(z1.y);
      af[kt][6] = (short)f2bf(z1.z); af[kt][7] = (short)f2bf(z1.w);
    }
    float4v acch[NTH];
#pragma unroll
    for (int nt = 0; nt < NTH; nt++) {
      acch[nt] = (float4v){0.f, 0.f, 0.f, 0.f};
#pragma unroll
      for (int kt = 0; kt < KT; kt++) acch[nt] = mfma16(af[kt], m1f[nt][kt], acch[nt]);
    }
#pragma unroll
    for (int nt = 0; nt < NTH; nt++)
#pragma unroll
      for (int r = 0; r < 4; r++)
        *(unsigned short*)(yl + (rr + r) * LROW + (nt * 16 + nc) * 2) =
            f2bf(fmaxf(acch[nt][r], 0.f));
    asm volatile("" ::: "memory");
    short8v af2[KT];
#pragma unroll
    for (int kt = 0; kt < KT; kt++)
      af2[kt] = *(const short8v*)(yl + nc * LROW + kg * 16 + kt * 64);
    float4v acco[4];
#pragma unroll
    for (int nt = 0; nt < 4; nt++) {
      acco[nt] = (float4v){0.f, 0.f, 0.f, 0.f};
#pragma unroll
      for (int kt = 0; kt < KT; kt++) acco[nt] = mfma16(af2[kt], m2f[nt][kt], acco[nt]);
    }
#pragma unroll
    for (int nt = 0; nt < 4; nt++)
#pragma unroll
      for (int r = 0; r < 4; r++) {
        int v = v0 + rr + r;
        if (v < n_nodes)
          xout[(size_t)v * 64 + nt * 16 + nc] =
              fmaf(fmaxf(acco[nt][r], 0.f), scv[nt], shv[nt]);
      }
    asm volatile("" ::: "memory");
  }
}

// ---------------- graph mean-pool of concat(x1..x4) ----------------
__global__ __launch_bounds__(256) void pool_kernel(
    const float* __restrict__ x1, const float* __restrict__ x2,
    const float* __restrict__ x3, const float* __restrict__ x4,
    const int* __restrict__ goff, float* __restrict__ pooled, int G) {
  int g = blockIdx.x;
  int c = threadIdx.x;
  int sel = c >> 6, f = c & 63;
  const float* x = (sel == 0) ? x1 : (sel == 1) ? x2 : (sel == 2) ? x3 : x4;
  int s = goff[g], e = goff[g + 1];
  float acc = 0.f;
  for (int v = s; v < e; v++) acc += x[(size_t)v * 64 + f];
  float cnt = (float)(e - s);
  pooled[g * 256 + c] = acc / fmaxf(cnt, 1.0f);
}

// ---------------- FC head ----------------
__global__ __launch_bounds__(64) void head_kernel(
    const float* __restrict__ pooled,
    const float* __restrict__ w1, const float* __restrict__ b1,
    const float* __restrict__ w2, const float* __restrict__ b2,
    const float* __restrict__ w3, const float* __restrict__ b3,
    const float* __restrict__ w4, const float* __restrict__ b4,
    float* __restrict__ out, int G) {
  int g = blockIdx.x;
  int lane = threadIdx.x;
  __shared__ float sh[256];
  for (int i = lane; i < 256; i += 64) sh[i] = pooled[g * 256 + i];
  __syncthreads();
  float h1 = b1[lane];
#pragma unroll 8
  for (int i = 0; i < 256; i++) h1 = fmaf(sh[i], w1[i * 64 + lane], h1);
  h1 = fmaxf(h1, 0.f);
  __syncthreads();
  sh[lane] = h1;
  __syncthreads();
  float h2 = b2[lane];
#pragma unroll
  for (int i = 0; i < 64; i++) h2 = fmaf(sh[i], w2[i * 64 + lane], h2);
  h2 = fmaxf(h2, 0.f);
  __syncthreads();
  sh[lane] = h2;
  __syncthreads();
  float h3 = b3[lane];
#pragma unroll
  for (int i = 0; i < 64; i++) h3 = fmaf(sh[i], w3[i * 64 + lane], h3);
  h3 = fmaxf(h3, 0.f);
  float p = h3 * w4[lane];
  for (int d = 32; d > 0; d >>= 1) p += __shfl_down(p, d);
  if (lane == 0) out[g] = p + b4[0];
}

// ---------------------------------------------------------------------------

extern "C" void kernel_launch(void* const* d_in, const int* in_sizes, int n_in,
                              void* d_out, int out_size, void* d_ws, size_t ws_size,
                              hipStream_t stream) {
  const float* x      = (const float*)d_in[0];
  const float* eattr  = (const float*)d_in[1];
  const float* c1_be1 = (const float*)d_in[2];
  const float* c1_be2 = (const float*)d_in[3];
  const float* c1_m1  = (const float*)d_in[4];
  const float* c1_m2  = (const float*)d_in[5];
  const float* c1_eps = (const float*)d_in[6];
  const float* c2_be1 = (const float*)d_in[7];
  const float* c2_be2 = (const float*)d_in[8];
  const float* c2_m1  = (const float*)d_in[9];
  const float* c2_m2  = (const float*)d_in[10];
  const float* c2_eps = (const float*)d_in[11];
  const float* c3_be1 = (const float*)d_in[12];
  const float* c3_be2 = (const float*)d_in[13];
  const float* c3_m1  = (const float*)d_in[14];
  const float* c3_m2  = (const float*)d_in[15];
  const float* c3_eps = (const float*)d_in[16];
  const float* bn_g[4] = {(const float*)d_in[17], (const float*)d_in[21],
                          (const float*)d_in[25], (const float*)d_in[29]};
  const float* bn_b[4] = {(const float*)d_in[18], (const float*)d_in[22],
                          (const float*)d_in[26], (const float*)d_in[30]};
  const float* bn_m[4] = {(const float*)d_in[19], (const float*)d_in[23],
                          (const float*)d_in[27], (const float*)d_in[31]};
  const float* bn_v[4] = {(const float*)d_in[20], (const float*)d_in[24],
                          (const float*)d_in[28], (const float*)d_in[32]};
  const float* fc1_w = (const float*)d_in[33];
  const float* fc1_b = (const float*)d_in[34];
  const float* fc2_w = (const float*)d_in[35];
  const float* fc2_b = (const float*)d_in[36];
  const float* fc3_w = (const float*)d_in[37];
  const float* fc3_b = (const float*)d_in[38];
  const float* fc4_w = (const float*)d_in[39];
  const float* fc4_b = (const float*)d_in[40];
  const int* eidx  = (const int*)d_in[41];
  const int* batch = (const int*)d_in[42];

  const int N = in_sizes[0] / 28;
  const int E = in_sizes[1] / 3;
  const int G = out_size;
  const int* src = eidx;
  const int* dst = eidx + E;
  float* outf = (float*)d_out;

  char* p = (char*)d_ws;
  auto alloc = [&](size_t bytes) {
    char* r = p;
    p += (bytes + 255) & ~(size_t)255;
    return r;
  };
  const int NBLK = (N + 255) / 256;
  int* counts   = (int*)alloc((size_t)N * 4);
  int* offs     = (int*)alloc((size_t)(N + 1) * 4);
  int* cursor   = (int*)alloc((size_t)N * 4);
  int* bsum     = (int*)alloc((size_t)NBLK * 4);
  int* goff     = (int*)alloc((size_t)(G + 1) * 4);
  int* src_s    = (int*)alloc((size_t)E * 4);
  float4* attr_s = (float4*)alloc((size_t)E * 16);
  unsigned short* FB = (unsigned short*)alloc(9 * 4096 * 2);
  float* B1P    = (float*)alloc(3 * 64 * 48 * 4);
  unsigned short* ebond = (unsigned short*)alloc((size_t)E * 64 * 2);
  float* zbuf   = (float*)alloc((size_t)N * 64 * 4);
  float* x1     = (float*)alloc((size_t)N * 64 * 4);
  float* x2     = (float*)alloc((size_t)N * 64 * 4);
  float* x3     = (float*)alloc((size_t)N * 64 * 4);
  float* x4     = (float*)alloc((size_t)N * 64 * 4);
  float* pooled = (float*)alloc((size_t)G * 256 * 4);
  (void)ws_size; (void)n_in;

  prep_kernel<<<12, 256, 0, stream>>>(c1_be2, c2_be2, c3_be2, c1_m1, c2_m1, c3_m1,
                                      c1_m2, c2_m2, c3_m2, c1_be1, c2_be1, c3_be1,
                                      FB, B1P);
  hipMemsetAsync(counts, 0, (size_t)N * 4, stream);
  hist_kernel<<<1024, 256, 0, stream>>>(dst, counts, E);
  boundary_kernel<<<(G + 128) / 128, 128, 0, stream>>>(batch, goff, N, G);
  block_reduce_kernel<<<NBLK, 256, 0, stream>>>(counts, bsum, N);
  bsum_scan_kernel<<<1, 256, 0, stream>>>(bsum, NBLK);
  scan_apply_kernel<<<NBLK, 256, 0, stream>>>(counts, bsum, offs, cursor, N);
  fill_perm_kernel<<<1024, 256, 0, stream>>>(src, dst, eattr, cursor, src_s, attr_s, E);

  unsigned short* FB_be2[3] = {FB + 0 * 4096, FB + 1 * 4096, FB + 2 * 4096};
  unsigned short* FB_m1[3]  = {FB + 3 * 4096, FB + 4 * 4096, FB + 5 * 4096};
  unsigned short* FB_m2[3]  = {FB + 6 * 4096, FB + 7 * 4096, FB + 8 * 4096};
  float* B1[3] = {B1P, B1P + 64 * 48, B1P + 2 * 64 * 48};

  dim3 blk(256);
  const int AGGB = (N + 15) / 16;  // 4 waves/block x 4 nodes/wave
  // layer 1
  bond_kernel<28><<<1024, blk, 0, stream>>>(attr_s, B1[0], FB_be2[0], ebond, E);
  agg_kernel<28, 32><<<AGGB, blk, 0, stream>>>(x, ebond, c1_eps, src_s, offs, zbuf, N, E);
  node_mfma_kernel<28><<<512, blk, 0, stream>>>(zbuf, FB_m1[0], FB_m2[0], bn_g[0],
                                                bn_b[0], bn_m[0], bn_v[0], x1, N);
  // layer 2
  bond_kernel<64><<<1024, blk, 0, stream>>>(attr_s, B1[1], FB_be2[1], ebond, E);
  agg_kernel<64, 64><<<AGGB, blk, 0, stream>>>(x1, ebond, c2_eps, src_s, offs, zbuf, N, E);
  node_mfma_kernel<64><<<512, blk, 0, stream>>>(zbuf, FB_m1[1], FB_m2[1], bn_g[1],
                                                bn_b[1], bn_m[1], bn_v[1], x2, N);
  // layer 3
  bond_kernel<64><<<1024, blk, 0, stream>>>(attr_s, B1[2], FB_be2[2], ebond, E);
  agg_kernel<64, 64><<<AGGB, blk, 0, stream>>>(x2, ebond, c3_eps, src_s, offs, zbuf, N, E);
  node_mfma_kernel<64><<<512, blk, 0, stream>>>(zbuf, FB_m1[2], FB_m2[2], bn_g[2],
                                                bn_b[2], bn_m[2], bn_v[2], x3, N);
  // layer 4 (conv3 weights reused -> ebond already holds c3 bond encodings)
  agg_kernel<64, 64><<<AGGB, blk, 0, stream>>>(x3, ebond, c3_eps, src_s, offs, zbuf, N, E);
  node_mfma_kernel<64><<<512, blk, 0, stream>>>(zbuf, FB_m1[2], FB_m2[2], bn_g[3],
                                                bn_b[3], bn_m[3], bn_v[3], x4, N);

  pool_kernel<<<G, blk, 0, stream>>>(x1, x2, x3, x4, goff, pooled, G);
  head_kernel<<<G, 64, 0, stream>>>(pooled, fc1_w, fc1_b, fc2_w, fc2_b, fc3_w,
                                    fc3_b, fc4_w, fc4_b, outf, G);
}

// Round 12
// 633.646 us; speedup vs baseline: 1.6756x; 1.1210x over previous
//
#include <hip/hip_runtime.h>

// ---------------------------------------------------------------------------
// NetGINE round 10 (base r7, restructured edge phase):
//   bond_m_kernel (edge-parallel): e = relu(attr@be1)@be2 via MFMA, gather
//       h[src] (no dependency chain - all gathers independent), store
//       m = relu(h[src]+e) as bf16 in dst-sorted order.
//   aggm_kernel (node-parallel): z[v] = (1+eps)h[v] + sum m[contiguous rows]
//       -- pure streaming, no gather, no atomics.
//   node_mfma_kernel: x = bn(relu(relu(z@m1)@m2))  (unchanged)
//   CSR build + prep + pool + head unchanged from r7.
//   Layer 4 re-runs bond_m with conv3 weights (h differs).
// ---------------------------------------------------------------------------

typedef __attribute__((ext_vector_type(8))) short short8v;
typedef __attribute__((ext_vector_type(4))) float float4v;

__device__ __forceinline__ unsigned short f2bf(float f) {  // RNE f32->bf16
  unsigned u = __float_as_uint(f);
  u += 0x7fff + ((u >> 16) & 1);
  return (unsigned short)(u >> 16);
}
__device__ __forceinline__ float bf2f(unsigned short s) {
  return __uint_as_float(((unsigned)s) << 16);
}
__device__ __forceinline__ float4v mfma16(short8v a, short8v b, float4v c) {
  return __builtin_amdgcn_mfma_f32_16x16x32_bf16(a, b, c, 0, 0, 0);
}

// ---------------- weight prep: frag-layout bf16 buffers ----------------
__global__ __launch_bounds__(256) void prep_kernel(
    const float* c1be2, const float* c2be2, const float* c3be2,
    const float* c1m1, const float* c2m1, const float* c3m1,
    const float* c1m2, const float* c2m2, const float* c3m2,
    const float* c1be1, const float* c2be1, const float* c3be1,
    unsigned short* FB, float* B1P) {
  int job = blockIdx.x;
  if (job < 9) {
    const float* W = nullptr; int ldw = 0, kmax = 0, nmax = 0, NT = 0, KT = 0;
    switch (job) {
      case 0: W = c1be2; ldw = 28; kmax = 28; nmax = 28; NT = 2; KT = 1; break;
      case 1: W = c2be2; ldw = 64; kmax = 64; nmax = 64; NT = 4; KT = 2; break;
      case 2: W = c3be2; ldw = 64; kmax = 64; nmax = 64; NT = 4; KT = 2; break;
      case 3: W = c1m1;  ldw = 28; kmax = 28; nmax = 28; NT = 2; KT = 1; break;
      case 4: W = c2m1;  ldw = 64; kmax = 64; nmax = 64; NT = 4; KT = 2; break;
      case 5: W = c3m1;  ldw = 64; kmax = 64; nmax = 64; NT = 4; KT = 2; break;
      case 6: W = c1m2;  ldw = 64; kmax = 28; nmax = 64; NT = 4; KT = 1; break;
      case 7: W = c2m2;  ldw = 64; kmax = 64; nmax = 64; NT = 4; KT = 2; break;
      case 8: W = c3m2;  ldw = 64; kmax = 64; nmax = 64; NT = 4; KT = 2; break;
    }
    unsigned short* out = FB + (size_t)job * 4096;
    int total = NT * KT * 512;
    for (int i = threadIdx.x; i < total; i += 256) {
      int fi = i >> 9, l = (i >> 3) & 63, j = i & 7;
      int kt = fi % KT, nt = fi / KT;
      int k = kt * 32 + (l >> 4) * 8 + j;
      int n = nt * 16 + (l & 15);
      float w = (k < kmax && n < nmax) ? W[k * ldw + n] : 0.f;
      out[i] = f2bf(w);
    }
  } else {
    int b = job - 9;
    const float* be1 = (b == 0) ? c1be1 : (b == 1) ? c2be1 : c3be1;
    int DE = (b == 0) ? 28 : 64;
    float* out = B1P + (size_t)b * (64 * 48);
    for (int i = threadIdx.x; i < 64 * 48; i += 256) {
      int l = i / 48, r = i % 48;
      int c = r / 16, kk = r % 16;
      int kt = kk >> 3, j = kk & 7;
      int k = kt * 32 + ((l >> 4) & 3) * 8 + j;
      out[i] = (k < DE) ? be1[c * DE + k] : 0.f;
    }
  }
}

// ---------------- CSR build ----------------

__global__ void hist_kernel(const int* __restrict__ idx, int* __restrict__ cnt, int n) {
  int i = blockIdx.x * blockDim.x + threadIdx.x;
  int stride = gridDim.x * blockDim.x;
  for (; i < n; i += stride) atomicAdd(&cnt[idx[i]], 1);
}

__global__ void fill_perm_kernel(const int* __restrict__ srcs, const int* __restrict__ dsts,
                                 const float* __restrict__ eattr, int* __restrict__ cursor,
                                 int* __restrict__ src_s, float4* __restrict__ attr_s,
                                 int n) {
  int i = blockIdx.x * blockDim.x + threadIdx.x;
  int stride = gridDim.x * blockDim.x;
  for (; i < n; i += stride) {
    int d = dsts[i];
    int p = atomicAdd(&cursor[d], 1);
    src_s[p] = srcs[i];
    attr_s[p] = make_float4(eattr[i * 3 + 0], eattr[i * 3 + 1], eattr[i * 3 + 2], 0.f);
  }
}

__global__ __launch_bounds__(256) void block_reduce_kernel(
    const int* __restrict__ cnt, int* __restrict__ bsum, int n) {
  __shared__ int s[256];
  int i = blockIdx.x * 256 + threadIdx.x;
  s[threadIdx.x] = (i < n) ? cnt[i] : 0;
  __syncthreads();
  for (int d = 128; d > 0; d >>= 1) {
    if (threadIdx.x < d) s[threadIdx.x] += s[threadIdx.x + d];
    __syncthreads();
  }
  if (threadIdx.x == 0) bsum[blockIdx.x] = s[0];
}

__global__ __launch_bounds__(256) void bsum_scan_kernel(int* __restrict__ bsum, int nb) {
  __shared__ int s[1024];
  for (int i = threadIdx.x; i < 1024; i += 256) s[i] = (i < nb) ? bsum[i] : 0;
  __syncthreads();
  if (threadIdx.x == 0) {
    int acc = 0;
    for (int i = 0; i < nb; i++) { int t = s[i]; s[i] = acc; acc += t; }
  }
  __syncthreads();
  for (int i = threadIdx.x; i < nb; i += 256) bsum[i] = s[i];
}

__global__ __launch_bounds__(256) void scan_apply_kernel(
    const int* __restrict__ cnt, const int* __restrict__ bsum,
    int* __restrict__ offs, int* __restrict__ cursor, int n) {
  __shared__ int s[256];
  int b = blockIdx.x;
  int i = b * 256 + threadIdx.x;
  int v = (i < n) ? cnt[i] : 0;
  s[threadIdx.x] = v;
  __syncthreads();
  for (int d = 1; d < 256; d <<= 1) {
    int t = (threadIdx.x >= d) ? s[threadIdx.x - d] : 0;
    __syncthreads();
    s[threadIdx.x] += t;
    __syncthreads();
  }
  int excl = s[threadIdx.x] - v + bsum[b];
  if (i < n) { offs[i] = excl; cursor[i] = excl; }
  if (i == n - 1) offs[n] = excl + v;
}

__global__ void boundary_kernel(const int* __restrict__ batch, int* __restrict__ goff,
                                int n, int G) {
  int g = blockIdx.x * blockDim.x + threadIdx.x;
  if (g > G) return;
  int lo = 0, hi = n;
  while (lo < hi) {
    int mid = (lo + hi) >> 1;
    if (batch[mid] < g) lo = mid + 1; else hi = mid;
  }
  goff[g] = lo;
}

// ---------------- fused bond + gather -> m (edge-parallel, no atomics) ------
// Per 16-edge tile (dst-sorted): e = relu(attr@be1)@be2 via MFMA (in regs),
// gather h[src_row] for the 4 rows this lane owns (independent loads),
// store m = relu(h+e) bf16 rows. DE = h row width (28 or 64); m row = RB.
template <int DE>
__global__ __launch_bounds__(256) void bond_m_kernel(
    const float4* __restrict__ attr_s, const float* __restrict__ b1p,
    const unsigned short* __restrict__ be2f, const float* __restrict__ h,
    const int* __restrict__ src_s, unsigned short* __restrict__ m_out, int E) {
  constexpr int KT = (DE + 31) / 32;
  constexpr int NT = (DE + 15) / 16;
  constexpr int RB = KT * 32;
  int lane = threadIdx.x & 63;
  int nc = lane & 15, rr = (lane >> 4) * 4;
  int gw = (blockIdx.x * blockDim.x + threadIdx.x) >> 6;
  int nw = (gridDim.x * blockDim.x) >> 6;

  float b1v[3][KT * 8];
#pragma unroll
  for (int c = 0; c < 3; c++)
#pragma unroll
    for (int kk = 0; kk < KT * 8; kk++)
      b1v[c][kk] = b1p[lane * 48 + c * 16 + (kk >> 3) * 8 + (kk & 7)];

  short8v bfrag[NT][KT];
#pragma unroll
  for (int nt = 0; nt < NT; nt++)
#pragma unroll
    for (int kt = 0; kt < KT; kt++)
      bfrag[nt][kt] = *(const short8v*)(be2f + ((nt * KT + kt) * 64 + lane) * 8);

  bool colv[NT];
#pragma unroll
  for (int nt = 0; nt < NT; nt++) colv[nt] = (DE == 64) || (nt * 16 + nc < DE);

  int ntiles = (E + 15) >> 4;
  for (int tile = gw; tile < ntiles; tile += nw) {
    int j0 = tile << 4;
    // bond encoder A-frag (edge row = nc)
    float4 a = attr_s[min(j0 + nc, E - 1)];
    short8v af[KT];
#pragma unroll
    for (int kt = 0; kt < KT; kt++)
#pragma unroll
      for (int j = 0; j < 8; j++) {
        int kk = kt * 8 + j;
        float t = fmaxf(fmaf(a.x, b1v[0][kk], fmaf(a.y, b1v[1][kk], a.z * b1v[2][kk])), 0.f);
        af[kt][j] = (short)f2bf(t);
      }
    float4v acc[NT];
#pragma unroll
    for (int nt = 0; nt < NT; nt++) {
      acc[nt] = (float4v){0.f, 0.f, 0.f, 0.f};
#pragma unroll
      for (int kt = 0; kt < KT; kt++) acc[nt] = mfma16(af[kt], bfrag[nt][kt], acc[nt]);
    }
    // rows owned by this lane: j0+rr+r ; gather h[src] (independent loads)
    int s_r[4];
    bool rv[4];
#pragma unroll
    for (int r = 0; r < 4; r++) {
      int jr = j0 + rr + r;
      rv[r] = jr < E;
      s_r[r] = src_s[min(jr, E - 1)];
    }
    float hv[4][NT];
#pragma unroll
    for (int r = 0; r < 4; r++)
#pragma unroll
      for (int nt = 0; nt < NT; nt++)
        hv[r][nt] = colv[nt] ? h[(size_t)s_r[r] * DE + nt * 16 + nc] : 0.f;
    // m = relu(h + e), store bf16
#pragma unroll
    for (int r = 0; r < 4; r++) {
      if (rv[r]) {
#pragma unroll
        for (int nt = 0; nt < NT; nt++) {
          float mv = colv[nt] ? fmaxf(hv[r][nt] + acc[nt][r], 0.f) : 0.f;
          m_out[(size_t)(j0 + rr + r) * RB + nt * 16 + nc] = f2bf(mv);
        }
      }
    }
  }
}

// ---------------- streaming aggregation (no gather, no atomics) -------------
// z[v] = (1+eps)*h[v] + sum_{j=offs[v]}^{offs[v+1]} m[j]   (contiguous rows)
template <int DH, int RB>
__global__ __launch_bounds__(256) void aggm_kernel(
    const float* __restrict__ h, const unsigned short* __restrict__ m,
    const float* __restrict__ epsp, const int* __restrict__ offs,
    float* __restrict__ zout, int n_nodes) {
  int wid = (blockIdx.x * blockDim.x + threadIdx.x) >> 6;
  int nw = (gridDim.x * blockDim.x) >> 6;
  int lane = threadIdx.x & 63;
  float eps1 = 1.f + epsp[0];
  const bool hl = (DH == 64) || (lane < DH);
  const bool el = (RB == 64) || (lane < RB);
  for (int v = wid; v < n_nodes; v += nw) {
    float acc = hl ? eps1 * h[(size_t)v * DH + lane] : 0.f;
    int j = offs[v], e1 = offs[v + 1];
    if (el) {
      for (; j + 4 <= e1; j += 4) {
        float b0 = bf2f(m[(size_t)j * RB + lane]);
        float b1 = bf2f(m[(size_t)(j + 1) * RB + lane]);
        float b2 = bf2f(m[(size_t)(j + 2) * RB + lane]);
        float b3 = bf2f(m[(size_t)(j + 3) * RB + lane]);
        acc += (b0 + b1) + (b2 + b3);
      }
      for (; j < e1; j++) acc += bf2f(m[(size_t)j * RB + lane]);
      zout[(size_t)v * RB + lane] = acc;
    }
  }
}

// ---------------- node MLP + relu + BN (MFMA) ----------------
template <int DIN>
__global__ __launch_bounds__(256) void node_mfma_kernel(
    const float* __restrict__ z, const unsigned short* __restrict__ m1f_g,
    const unsigned short* __restrict__ m2f_g, const float* __restrict__ bng,
    const float* __restrict__ bnb, const float* __restrict__ bnm,
    const float* __restrict__ bnv, float* __restrict__ xout, int n_nodes) {
  constexpr int KT = (DIN + 31) / 32;
  constexpr int NTH = (DIN + 15) / 16;
  constexpr int ZR = KT * 32;
  constexpr int LROW = 64 * 2 + 16;
  __shared__ __attribute__((aligned(16))) char lds_all[4 * 16 * LROW];
  char* yl = lds_all + (threadIdx.x >> 6) * (16 * LROW);
  int lane = threadIdx.x & 63;
  int nc = lane & 15, kg = lane >> 4, rr = kg * 4;
  int gw = (blockIdx.x * blockDim.x + threadIdx.x) >> 6;
  int nw = (gridDim.x * blockDim.x) >> 6;

  short8v m1f[NTH][KT], m2f[4][KT];
#pragma unroll
  for (int nt = 0; nt < NTH; nt++)
#pragma unroll
    for (int kt = 0; kt < KT; kt++)
      m1f[nt][kt] = *(const short8v*)(m1f_g + ((nt * KT + kt) * 64 + lane) * 8);
#pragma unroll
  for (int nt = 0; nt < 4; nt++)
#pragma unroll
    for (int kt = 0; kt < KT; kt++)
      m2f[nt][kt] = *(const short8v*)(m2f_g + ((nt * KT + kt) * 64 + lane) * 8);

  float scv[4], shv[4];
#pragma unroll
  for (int nt = 0; nt < 4; nt++) {
    int f = nt * 16 + nc;
    float sc = bng[f] * rsqrtf(bnv[f] + 1e-5f);
    scv[nt] = sc;
    shv[nt] = bnb[f] - bnm[f] * sc;
  }

  int ntiles = (n_nodes + 15) >> 4;
  for (int tile = gw; tile < ntiles; tile += nw) {
    int v0 = tile << 4;
    int vr = min(v0 + nc, n_nodes - 1);
    short8v af[KT];
#pragma unroll
    for (int kt = 0; kt < KT; kt++) {
      const float* zp = z + (size_t)vr * ZR + kt * 32 + kg * 8;
      float4 z0 = *(const float4*)(zp);
      float4 z1 = *(const float4*)(zp + 4);
      af[kt][0] = (short)f2bf(z0.x); af[kt][1] = (short)f2bf(z0.y);
      af[kt][2] = (short)f2bf(z0.z); af[kt][3] = (short)f2bf(z0.w);
      af[kt][4] = (short)f2bf(z1.x); af[kt][5] = (short)f2bf(z1.y);
      af[kt][6] = (short)f2bf(z1.z); af[kt][7] = (short)f2bf(z1.w);
    }
    float4v acch[NTH];
#pragma unroll
    for (int nt = 0; nt < NTH; nt++) {
      acch[nt] = (float4v){0.f, 0.f, 0.f, 0.f};
#pragma unroll
      for (int kt = 0; kt < KT; kt++) acch[nt] = mfma16(af[kt], m1f[nt][kt], acch[nt]);
    }
#pragma unroll
    for (int nt = 0; nt < NTH; nt++)
#pragma unroll
      for (int r = 0; r < 4; r++)
        *(unsigned short*)(yl + (rr + r) * LROW + (nt * 16 + nc) * 2) =
            f2bf(fmaxf(acch[nt][r], 0.f));
    asm volatile("" ::: "memory");
    short8v af2[KT];
#pragma unroll
    for (int kt = 0; kt < KT; kt++)
      af2[kt] = *(const short8v*)(yl + nc * LROW + kg * 16 + kt * 64);
    float4v acco[4];
#pragma unroll
    for (int nt = 0; nt < 4; nt++) {
      acco[nt] = (float4v){0.f, 0.f, 0.f, 0.f};
#pragma unroll
      for (int kt = 0; kt < KT; kt++) acco[nt] = mfma16(af2[kt], m2f[nt][kt], acco[nt]);
    }
#pragma unroll
    for (int nt = 0; nt < 4; nt++)
#pragma unroll
      for (int r = 0; r < 4; r++) {
        int v = v0 + rr + r;
        if (v < n_nodes)
          xout[(size_t)v * 64 + nt * 16 + nc] =
              fmaf(fmaxf(acco[nt][r], 0.f), scv[nt], shv[nt]);
      }
    asm volatile("" ::: "memory");
  }
}

// ---------------- graph mean-pool of concat(x1..x4) ----------------
__global__ __launch_bounds__(256) void pool_kernel(
    const float* __restrict__ x1, const float* __restrict__ x2,
    const float* __restrict__ x3, const float* __restrict__ x4,
    const int* __restrict__ goff, float* __restrict__ pooled, int G) {
  int g = blockIdx.x;
  int c = threadIdx.x;
  int sel = c >> 6, f = c & 63;
  const float* x = (sel == 0) ? x1 : (sel == 1) ? x2 : (sel == 2) ? x3 : x4;
  int s = goff[g], e = goff[g + 1];
  float acc = 0.f;
  for (int v = s; v < e; v++) acc += x[(size_t)v * 64 + f];
  float cnt = (float)(e - s);
  pooled[g * 256 + c] = acc / fmaxf(cnt, 1.0f);
}

// ---------------- FC head ----------------
__global__ __launch_bounds__(64) void head_kernel(
    const float* __restrict__ pooled,
    const float* __restrict__ w1, const float* __restrict__ b1,
    const float* __restrict__ w2, const float* __restrict__ b2,
    const float* __restrict__ w3, const float* __restrict__ b3,
    const float* __restrict__ w4, const float* __restrict__ b4,
    float* __restrict__ out, int G) {
  int g = blockIdx.x;
  int lane = threadIdx.x;
  __shared__ float sh[256];
  for (int i = lane; i < 256; i += 64) sh[i] = pooled[g * 256 + i];
  __syncthreads();
  float h1 = b1[lane];
#pragma unroll 8
  for (int i = 0; i < 256; i++) h1 = fmaf(sh[i], w1[i * 64 + lane], h1);
  h1 = fmaxf(h1, 0.f);
  __syncthreads();
  sh[lane] = h1;
  __syncthreads();
  float h2 = b2[lane];
#pragma unroll
  for (int i = 0; i < 64; i++) h2 = fmaf(sh[i], w2[i * 64 + lane], h2);
  h2 = fmaxf(h2, 0.f);
  __syncthreads();
  sh[lane] = h2;
  __syncthreads();
  float h3 = b3[lane];
#pragma unroll
  for (int i = 0; i < 64; i++) h3 = fmaf(sh[i], w3[i * 64 + lane], h3);
  h3 = fmaxf(h3, 0.f);
  float p = h3 * w4[lane];
  for (int d = 32; d > 0; d >>= 1) p += __shfl_down(p, d);
  if (lane == 0) out[g] = p + b4[0];
}

// ---------------------------------------------------------------------------

extern "C" void kernel_launch(void* const* d_in, const int* in_sizes, int n_in,
                              void* d_out, int out_size, void* d_ws, size_t ws_size,
                              hipStream_t stream) {
  const float* x      = (const float*)d_in[0];
  const float* eattr  = (const float*)d_in[1];
  const float* c1_be1 = (const float*)d_in[2];
  const float* c1_be2 = (const float*)d_in[3];
  const float* c1_m1  = (const float*)d_in[4];
  const float* c1_m2  = (const float*)d_in[5];
  const float* c1_eps = (const float*)d_in[6];
  const float* c2_be1 = (const float*)d_in[7];
  const float* c2_be2 = (const float*)d_in[8];
  const float* c2_m1  = (const float*)d_in[9];
  const float* c2_m2  = (const float*)d_in[10];
  const float* c2_eps = (const float*)d_in[11];
  const float* c3_be1 = (const float*)d_in[12];
  const float* c3_be2 = (const float*)d_in[13];
  const float* c3_m1  = (const float*)d_in[14];
  const float* c3_m2  = (const float*)d_in[15];
  const float* c3_eps = (const float*)d_in[16];
  const float* bn_g[4] = {(const float*)d_in[17], (const float*)d_in[21],
                          (const float*)d_in[25], (const float*)d_in[29]};
  const float* bn_b[4] = {(const float*)d_in[18], (const float*)d_in[22],
                          (const float*)d_in[26], (const float*)d_in[30]};
  const float* bn_m[4] = {(const float*)d_in[19], (const float*)d_in[23],
                          (const float*)d_in[27], (const float*)d_in[31]};
  const float* bn_v[4] = {(const float*)d_in[20], (const float*)d_in[24],
                          (const float*)d_in[28], (const float*)d_in[32]};
  const float* fc1_w = (const float*)d_in[33];
  const float* fc1_b = (const float*)d_in[34];
  const float* fc2_w = (const float*)d_in[35];
  const float* fc2_b = (const float*)d_in[36];
  const float* fc3_w = (const float*)d_in[37];
  const float* fc3_b = (const float*)d_in[38];
  const float* fc4_w = (const float*)d_in[39];
  const float* fc4_b = (const float*)d_in[40];
  const int* eidx  = (const int*)d_in[41];
  const int* batch = (const int*)d_in[42];

  const int N = in_sizes[0] / 28;
  const int E = in_sizes[1] / 3;
  const int G = out_size;
  const int* src = eidx;
  const int* dst = eidx + E;
  float* outf = (float*)d_out;

  char* p = (char*)d_ws;
  auto alloc = [&](size_t bytes) {
    char* r = p;
    p += (bytes + 255) & ~(size_t)255;
    return r;
  };
  const int NBLK = (N + 255) / 256;
  int* counts   = (int*)alloc((size_t)N * 4);
  int* offs     = (int*)alloc((size_t)(N + 1) * 4);
  int* cursor   = (int*)alloc((size_t)N * 4);
  int* bsum     = (int*)alloc((size_t)NBLK * 4);
  int* goff     = (int*)alloc((size_t)(G + 1) * 4);
  int* src_s    = (int*)alloc((size_t)E * 4);
  float4* attr_s = (float4*)alloc((size_t)E * 16);
  unsigned short* FB = (unsigned short*)alloc(9 * 4096 * 2);
  float* B1P    = (float*)alloc(3 * 64 * 48 * 4);
  unsigned short* mbuf = (unsigned short*)alloc((size_t)E * 64 * 2);
  float* zbuf   = (float*)alloc((size_t)N * 64 * 4);
  float* x1     = (float*)alloc((size_t)N * 64 * 4);
  float* x2     = (float*)alloc((size_t)N * 64 * 4);
  float* x3     = (float*)alloc((size_t)N * 64 * 4);
  float* x4     = (float*)alloc((size_t)N * 64 * 4);
  float* pooled = (float*)alloc((size_t)G * 256 * 4);
  (void)ws_size; (void)n_in;

  prep_kernel<<<12, 256, 0, stream>>>(c1_be2, c2_be2, c3_be2, c1_m1, c2_m1, c3_m1,
                                      c1_m2, c2_m2, c3_m2, c1_be1, c2_be1, c3_be1,
                                      FB, B1P);
  hipMemsetAsync(counts, 0, (size_t)N * 4, stream);
  hist_kernel<<<1024, 256, 0, stream>>>(dst, counts, E);
  boundary_kernel<<<(G + 128) / 128, 128, 0, stream>>>(batch, goff, N, G);
  block_reduce_kernel<<<NBLK, 256, 0, stream>>>(counts, bsum, N);
  bsum_scan_kernel<<<1, 256, 0, stream>>>(bsum, NBLK);
  scan_apply_kernel<<<NBLK, 256, 0, stream>>>(counts, bsum, offs, cursor, N);
  fill_perm_kernel<<<1024, 256, 0, stream>>>(src, dst, eattr, cursor, src_s, attr_s, E);

  unsigned short* FB_be2[3] = {FB + 0 * 4096, FB + 1 * 4096, FB + 2 * 4096};
  unsigned short* FB_m1[3]  = {FB + 3 * 4096, FB + 4 * 4096, FB + 5 * 4096};
  unsigned short* FB_m2[3]  = {FB + 6 * 4096, FB + 7 * 4096, FB + 8 * 4096};
  float* B1[3] = {B1P, B1P + 64 * 48, B1P + 2 * 64 * 48};

  dim3 blk(256);
  // layer 1
  bond_m_kernel<28><<<2048, blk, 0, stream>>>(attr_s, B1[0], FB_be2[0], x, src_s, mbuf, E);
  aggm_kernel<28, 32><<<2048, blk, 0, stream>>>(x, mbuf, c1_eps, offs, zbuf, N);
  node_mfma_kernel<28><<<512, blk, 0, stream>>>(zbuf, FB_m1[0], FB_m2[0], bn_g[0],
                                                bn_b[0], bn_m[0], bn_v[0], x1, N);
  // layer 2
  bond_m_kernel<64><<<2048, blk, 0, stream>>>(attr_s, B1[1], FB_be2[1], x1, src_s, mbuf, E);
  aggm_kernel<64, 64><<<2048, blk, 0, stream>>>(x1, mbuf, c2_eps, offs, zbuf, N);
  node_mfma_kernel<64><<<512, blk, 0, stream>>>(zbuf, FB_m1[1], FB_m2[1], bn_g[1],
                                                bn_b[1], bn_m[1], bn_v[1], x2, N);
  // layer 3
  bond_m_kernel<64><<<2048, blk, 0, stream>>>(attr_s, B1[2], FB_be2[2], x2, src_s, mbuf, E);
  aggm_kernel<64, 64><<<2048, blk, 0, stream>>>(x2, mbuf, c3_eps, offs, zbuf, N);
  node_mfma_kernel<64><<<512, blk, 0, stream>>>(zbuf, FB_m1[2], FB_m2[2], bn_g[2],
                                                bn_b[2], bn_m[2], bn_v[2], x3, N);
  // layer 4 (conv3 weights, h = x3 -> bond_m must re-run)
  bond_m_kernel<64><<<2048, blk, 0, stream>>>(attr_s, B1[2], FB_be2[2], x3, src_s, mbuf, E);
  aggm_kernel<64, 64><<<2048, blk, 0, stream>>>(x3, mbuf, c3_eps, offs, zbuf, N);
  node_mfma_kernel<64><<<512, blk, 0, stream>>>(zbuf, FB_m1[2], FB_m2[2], bn_g[3],
                                                bn_b[3], bn_m[3], bn_v[3], x4, N);

  pool_kernel<<<G, blk, 0, stream>>>(x1, x2, x3, x4, goff, pooled, G);
  head_kernel<<<G, 64, 0, stream>>>(pooled, fc1_w, fc1_b, fc2_w, fc2_b, fc3_w,
                                    fc3_b, fc4_w, fc4_b, outf, G);
}

// Round 13
// 591.553 us; speedup vs baseline: 1.7948x; 1.0712x over previous
//
#include <hip/hip_runtime.h>

// ---------------------------------------------------------------------------
// NetGINE round 13: r12's edge-parallel bond+gather, but m bounces through
// LDS (per-wave 16x65 f32 tile) instead of HBM; segmented reduce in-wave
// with boundary-only atomics (window-contiguous dsts).
//   init_z: z = (1+eps)h (base for boundary/zero-degree nodes)
//   fused_lds_kernel: per 64-edge window: {MFMA e -> gather h[src] -> m to
//       LDS -> transpose read -> segmented sum}; interior nodes plain-store,
//       boundary nodes unsafeAtomicAdd.
//   node_mfma_kernel / prep / CSR / pool / head unchanged from r12.
// ---------------------------------------------------------------------------

typedef __attribute__((ext_vector_type(8))) short short8v;
typedef __attribute__((ext_vector_type(4))) float float4v;

__device__ __forceinline__ unsigned short f2bf(float f) {  // RNE f32->bf16
  unsigned u = __float_as_uint(f);
  u += 0x7fff + ((u >> 16) & 1);
  return (unsigned short)(u >> 16);
}
__device__ __forceinline__ float bf2f(unsigned short s) {
  return __uint_as_float(((unsigned)s) << 16);
}
__device__ __forceinline__ float4v mfma16(short8v a, short8v b, float4v c) {
  return __builtin_amdgcn_mfma_f32_16x16x32_bf16(a, b, c, 0, 0, 0);
}

// ---------------- weight prep: frag-layout bf16 buffers ----------------
__global__ __launch_bounds__(256) void prep_kernel(
    const float* c1be2, const float* c2be2, const float* c3be2,
    const float* c1m1, const float* c2m1, const float* c3m1,
    const float* c1m2, const float* c2m2, const float* c3m2,
    const float* c1be1, const float* c2be1, const float* c3be1,
    unsigned short* FB, float* B1P) {
  int job = blockIdx.x;
  if (job < 9) {
    const float* W = nullptr; int ldw = 0, kmax = 0, nmax = 0, NT = 0, KT = 0;
    switch (job) {
      case 0: W = c1be2; ldw = 28; kmax = 28; nmax = 28; NT = 2; KT = 1; break;
      case 1: W = c2be2; ldw = 64; kmax = 64; nmax = 64; NT = 4; KT = 2; break;
      case 2: W = c3be2; ldw = 64; kmax = 64; nmax = 64; NT = 4; KT = 2; break;
      case 3: W = c1m1;  ldw = 28; kmax = 28; nmax = 28; NT = 2; KT = 1; break;
      case 4: W = c2m1;  ldw = 64; kmax = 64; nmax = 64; NT = 4; KT = 2; break;
      case 5: W = c3m1;  ldw = 64; kmax = 64; nmax = 64; NT = 4; KT = 2; break;
      case 6: W = c1m2;  ldw = 64; kmax = 28; nmax = 64; NT = 4; KT = 1; break;
      case 7: W = c2m2;  ldw = 64; kmax = 64; nmax = 64; NT = 4; KT = 2; break;
      case 8: W = c3m2;  ldw = 64; kmax = 64; nmax = 64; NT = 4; KT = 2; break;
    }
    unsigned short* out = FB + (size_t)job * 4096;
    int total = NT * KT * 512;
    for (int i = threadIdx.x; i < total; i += 256) {
      int fi = i >> 9, l = (i >> 3) & 63, j = i & 7;
      int kt = fi % KT, nt = fi / KT;
      int k = kt * 32 + (l >> 4) * 8 + j;
      int n = nt * 16 + (l & 15);
      float w = (k < kmax && n < nmax) ? W[k * ldw + n] : 0.f;
      out[i] = f2bf(w);
    }
  } else {
    int b = job - 9;
    const float* be1 = (b == 0) ? c1be1 : (b == 1) ? c2be1 : c3be1;
    int DE = (b == 0) ? 28 : 64;
    float* out = B1P + (size_t)b * (64 * 48);
    for (int i = threadIdx.x; i < 64 * 48; i += 256) {
      int l = i / 48, r = i % 48;
      int c = r / 16, kk = r % 16;
      int kt = kk >> 3, j = kk & 7;
      int k = kt * 32 + ((l >> 4) & 3) * 8 + j;
      out[i] = (k < DE) ? be1[c * DE + k] : 0.f;
    }
  }
}

// ---------------- CSR build ----------------

__global__ void hist_kernel(const int* __restrict__ idx, int* __restrict__ cnt, int n) {
  int i = blockIdx.x * blockDim.x + threadIdx.x;
  int stride = gridDim.x * blockDim.x;
  for (; i < n; i += stride) atomicAdd(&cnt[idx[i]], 1);
}

__global__ void fill_perm_kernel(const int* __restrict__ srcs, const int* __restrict__ dsts,
                                 const float* __restrict__ eattr, int* __restrict__ cursor,
                                 int* __restrict__ src_s, int* __restrict__ dst_s,
                                 float4* __restrict__ attr_s, int n) {
  int i = blockIdx.x * blockDim.x + threadIdx.x;
  int stride = gridDim.x * blockDim.x;
  for (; i < n; i += stride) {
    int d = dsts[i];
    int p = atomicAdd(&cursor[d], 1);
    src_s[p] = srcs[i];
    dst_s[p] = d;
    attr_s[p] = make_float4(eattr[i * 3 + 0], eattr[i * 3 + 1], eattr[i * 3 + 2], 0.f);
  }
}

__global__ __launch_bounds__(256) void block_reduce_kernel(
    const int* __restrict__ cnt, int* __restrict__ bsum, int n) {
  __shared__ int s[256];
  int i = blockIdx.x * 256 + threadIdx.x;
  s[threadIdx.x] = (i < n) ? cnt[i] : 0;
  __syncthreads();
  for (int d = 128; d > 0; d >>= 1) {
    if (threadIdx.x < d) s[threadIdx.x] += s[threadIdx.x + d];
    __syncthreads();
  }
  if (threadIdx.x == 0) bsum[blockIdx.x] = s[0];
}

__global__ __launch_bounds__(256) void bsum_scan_kernel(int* __restrict__ bsum, int nb) {
  __shared__ int s[1024];
  for (int i = threadIdx.x; i < 1024; i += 256) s[i] = (i < nb) ? bsum[i] : 0;
  __syncthreads();
  if (threadIdx.x == 0) {
    int acc = 0;
    for (int i = 0; i < nb; i++) { int t = s[i]; s[i] = acc; acc += t; }
  }
  __syncthreads();
  for (int i = threadIdx.x; i < nb; i += 256) bsum[i] = s[i];
}

__global__ __launch_bounds__(256) void scan_apply_kernel(
    const int* __restrict__ cnt, const int* __restrict__ bsum,
    int* __restrict__ cursor, int n) {
  __shared__ int s[256];
  int b = blockIdx.x;
  int i = b * 256 + threadIdx.x;
  int v = (i < n) ? cnt[i] : 0;
  s[threadIdx.x] = v;
  __syncthreads();
  for (int d = 1; d < 256; d <<= 1) {
    int t = (threadIdx.x >= d) ? s[threadIdx.x - d] : 0;
    __syncthreads();
    s[threadIdx.x] += t;
    __syncthreads();
  }
  int excl = s[threadIdx.x] - v + bsum[b];
  if (i < n) cursor[i] = excl;
}

__global__ void boundary_kernel(const int* __restrict__ batch, int* __restrict__ goff,
                                int n, int G) {
  int g = blockIdx.x * blockDim.x + threadIdx.x;
  if (g > G) return;
  int lo = 0, hi = n;
  while (lo < hi) {
    int mid = (lo + hi) >> 1;
    if (batch[mid] < g) lo = mid + 1; else hi = mid;
  }
  goff[g] = lo;
}

// ---------------- z init: z = (1+eps)*h, zero-padded to RB ----------------
template <int DH, int RB>
__global__ __launch_bounds__(256) void init_z_kernel(const float* __restrict__ h,
                                                     const float* __restrict__ epsp,
                                                     float* __restrict__ z, int n_nodes) {
  int i = blockIdx.x * blockDim.x + threadIdx.x;
  if (i >= n_nodes * RB) return;
  int v = i / RB, c = i % RB;
  float val = 0.f;
  if (DH == RB || c < DH) val = (1.f + epsp[0]) * h[(size_t)v * DH + c];
  z[i] = val;
}

// ---------------- fused edge kernel: bond MFMA + gather + LDS reduce --------
// Wave owns 64 contiguous dst-sorted edges (4x 16-edge MFMA tiles).
// m = relu(h[src]+e) goes to per-wave LDS (fp32), transpose-read so each
// lane owns one column, then wave-uniform segmented reduce over sorted dsts.
// Interior nodes (all edges in window): plain store z=(1+eps)h+sum.
// Boundary nodes (shared with neighbor windows): unsafeAtomicAdd onto init_z.
template <int DE>
__global__ __launch_bounds__(256) void fused_lds_kernel(
    const float4* __restrict__ attr_s, const float* __restrict__ b1p,
    const unsigned short* __restrict__ be2f, const float* __restrict__ h,
    const int* __restrict__ src_s, const int* __restrict__ dst_s,
    const float* __restrict__ epsp, float* __restrict__ z, int E) {
  constexpr int KT = (DE + 31) / 32;
  constexpr int NT = (DE + 15) / 16;
  constexpr int RB = KT * 32;
  constexpr int LW = 65;  // padded LDS row stride (words) -> spreads banks
  __shared__ float mlds_all[4][16 * LW];
  float* mlds = mlds_all[threadIdx.x >> 6];
  int lane = threadIdx.x & 63;
  int nc = lane & 15, rr = (lane >> 4) * 4;
  int wid = (blockIdx.x * blockDim.x + threadIdx.x) >> 6;
  float eps1 = 1.f + epsp[0];
  int win0 = wid << 6;
  if (win0 >= E) return;
  int win1 = min(win0 + 64, E);
  const bool el = (RB == 64) || (lane < RB);

  float b1v[3][KT * 8];
#pragma unroll
  for (int c = 0; c < 3; c++)
#pragma unroll
    for (int kk = 0; kk < KT * 8; kk++)
      b1v[c][kk] = b1p[lane * 48 + c * 16 + (kk >> 3) * 8 + (kk & 7)];

  short8v bfrag[NT][KT];
#pragma unroll
  for (int nt = 0; nt < NT; nt++)
#pragma unroll
    for (int kt = 0; kt < KT; kt++)
      bfrag[nt][kt] = *(const short8v*)(be2f + ((nt * KT + kt) * 64 + lane) * 8);

  bool colv[NT];
#pragma unroll
  for (int nt = 0; nt < NT; nt++) colv[nt] = (DE == 64) || (nt * 16 + nc < DE);

  // boundary detection: only first/last node of the window can be shared
  int d_prev = (win0 > 0) ? dst_s[win0 - 1] : -1;
  int d_next = (win1 < E) ? dst_s[win1] : -1;
  int cur = dst_s[win0];
  float racc = 0.f;

  for (int t = 0; t < 4; t++) {
    int j0 = win0 + (t << 4);
    if (j0 >= E) break;
    int nrows = min(16, E - j0);
    // --- bond encoder: e = relu(attr@be1)@be2 via MFMA ---
    float4 a = attr_s[min(j0 + nc, E - 1)];
    short8v af[KT];
#pragma unroll
    for (int kt = 0; kt < KT; kt++)
#pragma unroll
      for (int j = 0; j < 8; j++) {
        int kk = kt * 8 + j;
        float tt = fmaxf(fmaf(a.x, b1v[0][kk], fmaf(a.y, b1v[1][kk], a.z * b1v[2][kk])), 0.f);
        af[kt][j] = (short)f2bf(tt);
      }
    float4v acc[NT];
#pragma unroll
    for (int nt = 0; nt < NT; nt++) {
      acc[nt] = (float4v){0.f, 0.f, 0.f, 0.f};
#pragma unroll
      for (int kt = 0; kt < KT; kt++) acc[nt] = mfma16(af[kt], bfrag[nt][kt], acc[nt]);
    }
    // --- gather h[src] (independent loads), m = relu(h+e) -> LDS fp32 ---
    int s_r[4];
#pragma unroll
    for (int r = 0; r < 4; r++) s_r[r] = src_s[min(j0 + rr + r, E - 1)];
#pragma unroll
    for (int r = 0; r < 4; r++)
#pragma unroll
      for (int nt = 0; nt < NT; nt++) {
        float hv = colv[nt] ? h[(size_t)s_r[r] * DE + nt * 16 + nc] : 0.f;
        mlds[(rr + r) * LW + nt * 16 + nc] = fmaxf(hv + acc[nt][r], 0.f);
      }
    int dq = dst_s[min(j0 + nc, E - 1)];  // lane q<16 holds dst of row q
    asm volatile("s_waitcnt lgkmcnt(0)" ::: "memory");
    __builtin_amdgcn_sched_barrier(0);
    // --- transpose read: lane owns column `lane` for all 16 rows ---
    float mv[16];
#pragma unroll
    for (int q = 0; q < 16; q++) mv[q] = el ? mlds[q * LW + lane] : 0.f;
    // --- segmented reduce over sorted dsts ---
#pragma unroll
    for (int q = 0; q < 16; q++) {
      if (q < nrows) {
        int d = __builtin_amdgcn_readlane(dq, q);
        if (d != cur) {
          bool interior = (cur != d_prev) && (cur != d_next);
          if (el) {
            if (interior) {
              float hb = (DE == RB || lane < DE) ? eps1 * h[(size_t)cur * DE + lane] : 0.f;
              z[(size_t)cur * RB + lane] = hb + racc;
            } else {
              unsafeAtomicAdd(&z[(size_t)cur * RB + lane], racc);
            }
          }
          racc = 0.f;
          cur = d;
        }
        racc += mv[q];
      }
    }
    asm volatile("" ::: "memory");  // keep next tile's LDS writes below the reads
  }
  // final segment flush
  {
    bool interior = (cur != d_prev) && (cur != d_next);
    if (el) {
      if (interior) {
        float hb = (DE == RB || lane < DE) ? eps1 * h[(size_t)cur * DE + lane] : 0.f;
        z[(size_t)cur * RB + lane] = hb + racc;
      } else {
        unsafeAtomicAdd(&z[(size_t)cur * RB + lane], racc);
      }
    }
  }
}

// ---------------- node MLP + relu + BN (MFMA) ----------------
template <int DIN>
__global__ __launch_bounds__(256) void node_mfma_kernel(
    const float* __restrict__ z, const unsigned short* __restrict__ m1f_g,
    const unsigned short* __restrict__ m2f_g, const float* __restrict__ bng,
    const float* __restrict__ bnb, const float* __restrict__ bnm,
    const float* __restrict__ bnv, float* __restrict__ xout, int n_nodes) {
  constexpr int KT = (DIN + 31) / 32;
  constexpr int NTH = (DIN + 15) / 16;
  constexpr int ZR = KT * 32;
  constexpr int LROW = 64 * 2 + 16;
  __shared__ __attribute__((aligned(16))) char lds_all[4 * 16 * LROW];
  char* yl = lds_all + (threadIdx.x >> 6) * (16 * LROW);
  int lane = threadIdx.x & 63;
  int nc = lane & 15, kg = lane >> 4, rr = kg * 4;
  int gw = (blockIdx.x * blockDim.x + threadIdx.x) >> 6;
  int nw = (gridDim.x * blockDim.x) >> 6;

  short8v m1f[NTH][KT], m2f[4][KT];
#pragma unroll
  for (int nt = 0; nt < NTH; nt++)
#pragma unroll
    for (int kt = 0; kt < KT; kt++)
      m1f[nt][kt] = *(const short8v*)(m1f_g + ((nt * KT + kt) * 64 + lane) * 8);
#pragma unroll
  for (int nt = 0; nt < 4; nt++)
#pragma unroll
    for (int kt = 0; kt < KT; kt++)
      m2f[nt][kt] = *(const short8v*)(m2f_g + ((nt * KT + kt) * 64 + lane) * 8);

  float scv[4], shv[4];
#pragma unroll
  for (int nt = 0; nt < 4; nt++) {
    int f = nt * 16 + nc;
    float sc = bng[f] * rsqrtf(bnv[f] + 1e-5f);
    scv[nt] = sc;
    shv[nt] = bnb[f] - bnm[f] * sc;
  }

  int ntiles = (n_nodes + 15) >> 4;
  for (int tile = gw; tile < ntiles; tile += nw) {
    int v0 = tile << 4;
    int vr = min(v0 + nc, n_nodes - 1);
    short8v af[KT];
#pragma unroll
    for (int kt = 0; kt < KT; kt++) {
      const float* zp = z + (size_t)vr * ZR + kt * 32 + kg * 8;
      float4 z0 = *(const float4*)(zp);
      float4 z1 = *(const float4*)(zp + 4);
      af[kt][0] = (short)f2bf(z0.x); af[kt][1] = (short)f2bf(z0.y);
      af[kt][2] = (short)f2bf(z0.z); af[kt][3] = (short)f2bf(z0.w);
      af[kt][4] = (short)f2bf(z1.x); af[kt][5] = (short)f2bf(z1.y);
      af[kt][6] = (short)f2bf(z1.z); af[kt][7] = (short)f2bf(z1.w);
    }
    float4v acch[NTH];
#pragma unroll
    for (int nt = 0; nt < NTH; nt++) {
      acch[nt] = (float4v){0.f, 0.f, 0.f, 0.f};
#pragma unroll
      for (int kt = 0; kt < KT; kt++) acch[nt] = mfma16(af[kt], m1f[nt][kt], acch[nt]);
    }
#pragma unroll
    for (int nt = 0; nt < NTH; nt++)
#pragma unroll
      for (int r = 0; r < 4; r++)
        *(unsigned short*)(yl + (rr + r) * LROW + (nt * 16 + nc) * 2) =
            f2bf(fmaxf(acch[nt][r], 0.f));
    asm volatile("" ::: "memory");
    short8v af2[KT];
#pragma unroll
    for (int kt = 0; kt < KT; kt++)
      af2[kt] = *(const short8v*)(yl + nc * LROW + kg * 16 + kt * 64);
    float4v acco[4];
#pragma unroll
    for (int nt = 0; nt < 4; nt++) {
      acco[nt] = (float4v){0.f, 0.f, 0.f, 0.f};
#pragma unroll
      for (int kt = 0; kt < KT; kt++) acco[nt] = mfma16(af2[kt], m2f[nt][kt], acco[nt]);
    }
#pragma unroll
    for (int nt = 0; nt < 4; nt++)
#pragma unroll
      for (int r = 0; r < 4; r++) {
        int v = v0 + rr + r;
        if (v < n_nodes)
          xout[(size_t)v * 64 + nt * 16 + nc] =
              fmaf(fmaxf(acco[nt][r], 0.f), scv[nt], shv[nt]);
      }
    asm volatile("" ::: "memory");
  }
}

// ---------------- graph mean-pool of concat(x1..x4) ----------------
__global__ __launch_bounds__(256) void pool_kernel(
    const float* __restrict__ x1, const float* __restrict__ x2,
    const float* __restrict__ x3, const float* __restrict__ x4,
    const int* __restrict__ goff, float* __restrict__ pooled, int G) {
  int g = blockIdx.x;
  int c = threadIdx.x;
  int sel = c >> 6, f = c & 63;
  const float* x = (sel == 0) ? x1 : (sel == 1) ? x2 : (sel == 2) ? x3 : x4;
  int s = goff[g], e = goff[g + 1];
  float acc = 0.f;
  for (int v = s; v < e; v++) acc += x[(size_t)v * 64 + f];
  float cnt = (float)(e - s);
  pooled[g * 256 + c] = acc / fmaxf(cnt, 1.0f);
}

// ---------------- FC head ----------------
__global__ __launch_bounds__(64) void head_kernel(
    const float* __restrict__ pooled,
    const float* __restrict__ w1, const float* __restrict__ b1,
    const float* __restrict__ w2, const float* __restrict__ b2,
    const float* __restrict__ w3, const float* __restrict__ b3,
    const float* __restrict__ w4, const float* __restrict__ b4,
    float* __restrict__ out, int G) {
  int g = blockIdx.x;
  int lane = threadIdx.x;
  __shared__ float sh[256];
  for (int i = lane; i < 256; i += 64) sh[i] = pooled[g * 256 + i];
  __syncthreads();
  float h1 = b1[lane];
#pragma unroll 8
  for (int i = 0; i < 256; i++) h1 = fmaf(sh[i], w1[i * 64 + lane], h1);
  h1 = fmaxf(h1, 0.f);
  __syncthreads();
  sh[lane] = h1;
  __syncthreads();
  float h2 = b2[lane];
#pragma unroll
  for (int i = 0; i < 64; i++) h2 = fmaf(sh[i], w2[i * 64 + lane], h2);
  h2 = fmaxf(h2, 0.f);
  __syncthreads();
  sh[lane] = h2;
  __syncthreads();
  float h3 = b3[lane];
#pragma unroll
  for (int i = 0; i < 64; i++) h3 = fmaf(sh[i], w3[i * 64 + lane], h3);
  h3 = fmaxf(h3, 0.f);
  float p = h3 * w4[lane];
  for (int d = 32; d > 0; d >>= 1) p += __shfl_down(p, d);
  if (lane == 0) out[g] = p + b4[0];
}

// ---------------------------------------------------------------------------

extern "C" void kernel_launch(void* const* d_in, const int* in_sizes, int n_in,
                              void* d_out, int out_size, void* d_ws, size_t ws_size,
                              hipStream_t stream) {
  const float* x      = (const float*)d_in[0];
  const float* eattr  = (const float*)d_in[1];
  const float* c1_be1 = (const float*)d_in[2];
  const float* c1_be2 = (const float*)d_in[3];
  const float* c1_m1  = (const float*)d_in[4];
  const float* c1_m2  = (const float*)d_in[5];
  const float* c1_eps = (const float*)d_in[6];
  const float* c2_be1 = (const float*)d_in[7];
  const float* c2_be2 = (const float*)d_in[8];
  const float* c2_m1  = (const float*)d_in[9];
  const float* c2_m2  = (const float*)d_in[10];
  const float* c2_eps = (const float*)d_in[11];
  const float* c3_be1 = (const float*)d_in[12];
  const float* c3_be2 = (const float*)d_in[13];
  const float* c3_m1  = (const float*)d_in[14];
  const float* c3_m2  = (const float*)d_in[15];
  const float* c3_eps = (const float*)d_in[16];
  const float* bn_g[4] = {(const float*)d_in[17], (const float*)d_in[21],
                          (const float*)d_in[25], (const float*)d_in[29]};
  const float* bn_b[4] = {(const float*)d_in[18], (const float*)d_in[22],
                          (const float*)d_in[26], (const float*)d_in[30]};
  const float* bn_m[4] = {(const float*)d_in[19], (const float*)d_in[23],
                          (const float*)d_in[27], (const float*)d_in[31]};
  const float* bn_v[4] = {(const float*)d_in[20], (const float*)d_in[24],
                          (const float*)d_in[28], (const float*)d_in[32]};
  const float* fc1_w = (const float*)d_in[33];
  const float* fc1_b = (const float*)d_in[34];
  const float* fc2_w = (const float*)d_in[35];
  const float* fc2_b = (const float*)d_in[36];
  const float* fc3_w = (const float*)d_in[37];
  const float* fc3_b = (const float*)d_in[38];
  const float* fc4_w = (const float*)d_in[39];
  const float* fc4_b = (const float*)d_in[40];
  const int* eidx  = (const int*)d_in[41];
  const int* batch = (const int*)d_in[42];

  const int N = in_sizes[0] / 28;
  const int E = in_sizes[1] / 3;
  const int G = out_size;
  const int* src = eidx;
  const int* dst = eidx + E;
  float* outf = (float*)d_out;

  char* p = (char*)d_ws;
  auto alloc = [&](size_t bytes) {
    char* r = p;
    p += (bytes + 255) & ~(size_t)255;
    return r;
  };
  const int NBLK = (N + 255) / 256;
  int* counts   = (int*)alloc((size_t)N * 4);
  int* cursor   = (int*)alloc((size_t)N * 4);
  int* bsum     = (int*)alloc((size_t)NBLK * 4);
  int* goff     = (int*)alloc((size_t)(G + 1) * 4);
  int* src_s    = (int*)alloc((size_t)E * 4);
  int* dst_s    = (int*)alloc((size_t)E * 4);
  float4* attr_s = (float4*)alloc((size_t)E * 16);
  unsigned short* FB = (unsigned short*)alloc(9 * 4096 * 2);
  float* B1P    = (float*)alloc(3 * 64 * 48 * 4);
  float* zbuf   = (float*)alloc((size_t)N * 64 * 4);
  float* x1     = (float*)alloc((size_t)N * 64 * 4);
  float* x2     = (float*)alloc((size_t)N * 64 * 4);
  float* x3     = (float*)alloc((size_t)N * 64 * 4);
  float* x4     = (float*)alloc((size_t)N * 64 * 4);
  float* pooled = (float*)alloc((size_t)G * 256 * 4);
  (void)ws_size; (void)n_in;

  prep_kernel<<<12, 256, 0, stream>>>(c1_be2, c2_be2, c3_be2, c1_m1, c2_m1, c3_m1,
                                      c1_m2, c2_m2, c3_m2, c1_be1, c2_be1, c3_be1,
                                      FB, B1P);
  hipMemsetAsync(counts, 0, (size_t)N * 4, stream);
  hist_kernel<<<1024, 256, 0, stream>>>(dst, counts, E);
  boundary_kernel<<<(G + 128) / 128, 128, 0, stream>>>(batch, goff, N, G);
  block_reduce_kernel<<<NBLK, 256, 0, stream>>>(counts, bsum, N);
  bsum_scan_kernel<<<1, 256, 0, stream>>>(bsum, NBLK);
  scan_apply_kernel<<<NBLK, 256, 0, stream>>>(counts, bsum, cursor, N);
  fill_perm_kernel<<<1024, 256, 0, stream>>>(src, dst, eattr, cursor, src_s, dst_s,
                                             attr_s, E);

  unsigned short* FB_be2[3] = {FB + 0 * 4096, FB + 1 * 4096, FB + 2 * 4096};
  unsigned short* FB_m1[3]  = {FB + 3 * 4096, FB + 4 * 4096, FB + 5 * 4096};
  unsigned short* FB_m2[3]  = {FB + 6 * 4096, FB + 7 * 4096, FB + 8 * 4096};
  float* B1[3] = {B1P, B1P + 64 * 48, B1P + 2 * 64 * 48};

  dim3 blk(256);
  const int FEB = ((E + 63) / 64 + 3) / 4;  // one 64-edge window per wave
  // layer 1
  init_z_kernel<28, 32><<<(N * 32 + 255) / 256, blk, 0, stream>>>(x, c1_eps, zbuf, N);
  fused_lds_kernel<28><<<FEB, blk, 0, stream>>>(attr_s, B1[0], FB_be2[0], x, src_s,
                                                dst_s, c1_eps, zbuf, E);
  node_mfma_kernel<28><<<512, blk, 0, stream>>>(zbuf, FB_m1[0], FB_m2[0], bn_g[0],
                                                bn_b[0], bn_m[0], bn_v[0], x1, N);
  // layer 2
  init_z_kernel<64, 64><<<(N * 64 + 255) / 256, blk, 0, stream>>>(x1, c2_eps, zbuf, N);
  fused_lds_kernel<64><<<FEB, blk, 0, stream>>>(attr_s, B1[1], FB_be2[1], x1, src_s,
                                                dst_s, c2_eps, zbuf, E);
  node_mfma_kernel<64><<<512, blk, 0, stream>>>(zbuf, FB_m1[1], FB_m2[1], bn_g[1],
                                                bn_b[1], bn_m[1], bn_v[1], x2, N);
  // layer 3
  init_z_kernel<64, 64><<<(N * 64 + 255) / 256, blk, 0, stream>>>(x2, c3_eps, zbuf, N);
  fused_lds_kernel<64><<<FEB, blk, 0, stream>>>(attr_s, B1[2], FB_be2[2], x2, src_s,
                                                dst_s, c3_eps, zbuf, E);
  node_mfma_kernel<64><<<512, blk, 0, stream>>>(zbuf, FB_m1[2], FB_m2[2], bn_g[2],
                                                bn_b[2], bn_m[2], bn_v[2], x3, N);
  // layer 4 (conv3 weights reused; e recomputed)
  init_z_kernel<64, 64><<<(N * 64 + 255) / 256, blk, 0, stream>>>(x3, c3_eps, zbuf, N);
  fused_lds_kernel<64><<<FEB, blk, 0, stream>>>(attr_s, B1[2], FB_be2[2], x3, src_s,
                                                dst_s, c3_eps, zbuf, E);
  node_mfma_kernel<64><<<512, blk, 0, stream>>>(zbuf, FB_m1[2], FB_m2[2], bn_g[3],
                                                bn_b[3], bn_m[3], bn_v[3], x4, N);

  pool_kernel<<<G, blk, 0, stream>>>(x1, x2, x3, x4, goff, pooled, G);
  head_kernel<<<G, 64, 0, stream>>>(pooled, fc1_w, fc1_b, fc2_w, fc2_b, fc3_w,
                                    fc3_b, fc4_w, fc4_b, outf, G);
}